// Round 7
// baseline (303.841 us; speedup 1.0000x reference)
//
#include <hip/hip_runtime.h>

typedef unsigned short u16;
typedef unsigned char  u8;
typedef unsigned long long u64;
typedef __attribute__((ext_vector_type(8))) short bf16x8;   // 8 bf16 in 4 VGPRs
typedef __attribute__((ext_vector_type(4))) float f32x4;

constexpr int B_  = 2;
constexpr int S_  = 2048;
constexpr int D_  = 1024;
constexpr int H_  = 16;
constexpr int DK_ = 64;
constexpr int NROW = B_ * S_;                           // 4096
constexpr size_t QSZ  = (size_t)B_ * H_ * S_ * DK_;     // 4194304 elems per buffer
constexpr size_t XBSZ = (size_t)NROW * D_;              // 4194304 (one X matrix)
constexpr size_t WBSZ = (size_t)D_ * D_;                // 1048576 (one W matrix)
constexpr size_t MSZ  = (size_t)B_ * S_ * S_;           // 8388608 mask elems
constexpr size_t MPKB = MSZ / 8;                        // 1 MiB packed mask bytes
constexpr size_t NRH  = (size_t)B_ * H_ * S_;           // 65536 (b,h,s) rows

__device__ __forceinline__ u16 f2bf(float f) {
    union { float f; unsigned u; } c; c.f = f;
    unsigned r = c.u + 0x7fffu + ((c.u >> 16) & 1u);    // RNE
    return (u16)(r >> 16);
}
__device__ __forceinline__ unsigned pack2(float a, float b) {
    return (unsigned)f2bf(a) | ((unsigned)f2bf(b) << 16);
}
// HW packed f32->bf16 RNE: bit-identical to f2bf for finite values.
__device__ __forceinline__ unsigned cvt_pk_bf16(float a, float b) {
    unsigned r;
    asm("v_cvt_pk_bf16_f32 %0, %1, %2" : "=v"(r) : "v"(a), "v"(b));
    return r;
}

// async global->LDS, 16B per lane; lds ptr must be wave-uniform base
__device__ __forceinline__ void gl_lds16(const u16* g, u16* l) {
    __builtin_amdgcn_global_load_lds(
        (const __attribute__((address_space(1))) void*)g,
        (__attribute__((address_space(3))) void*)l, 16, 0, 0);
}

// ---------------------------------------------------------------------------
// cvt7m — UNCHANGED from R11. fp32 -> bf16 RNE of X/W + mask bit-pack.
// ---------------------------------------------------------------------------
__global__ __launch_bounds__(256)
void cvt7m(const float* __restrict__ s0, const float* __restrict__ s1,
           const float* __restrict__ s2, const float* __restrict__ s3,
           const float* __restrict__ s4, const float* __restrict__ s5,
           const float* __restrict__ s6, const int* __restrict__ mk,
           u16* __restrict__ d0, u16* __restrict__ d1, u16* __restrict__ d2,
           u16* __restrict__ d3, u16* __restrict__ d4, u16* __restrict__ d5,
           u16* __restrict__ d6, u8* __restrict__ mp)
{
    constexpr size_t XT = 3 * XBSZ;                            // 12582912
    constexpr int NCF = (int)((3 * XBSZ + 4 * WBSZ) / 2048);   // 8192
    constexpr int NCM = (int)(MSZ / 2048);                     // 4096

    for (int c = blockIdx.x; c < NCF + NCM; c += gridDim.x) {
        if (c < NCF) {
            const size_t base = (size_t)c * 2048;
            const float* s; u16* d; size_t off;
            if (base < XT) {
                const int a = (int)(base >> 22);
                off = base & (XBSZ - 1);
                s = (a == 0) ? s0 : (a == 1) ? s1 : s2;
                d = (a == 0) ? d0 : (a == 1) ? d1 : d2;
            } else {
                const size_t r = base - XT;
                const int a = (int)(r >> 20);
                off = r & (WBSZ - 1);
                s = (a == 0) ? s3 : (a == 1) ? s4 : (a == 2) ? s5 : s6;
                d = (a == 0) ? d3 : (a == 1) ? d4 : (a == 2) ? d5 : d6;
            }
            const size_t e = off + (size_t)threadIdx.x * 8;
            const float4 x0 = *(const float4*)(s + e);
            const float4 x1 = *(const float4*)(s + e + 4);
            uint4 p;
            p.x = pack2(x0.x, x0.y); p.y = pack2(x0.z, x0.w);
            p.z = pack2(x1.x, x1.y); p.w = pack2(x1.z, x1.w);
            *(uint4*)(d + e) = p;
        } else {
            const size_t e = (size_t)(c - NCF) * 2048 + (size_t)threadIdx.x * 8;
            const int4 x0 = *(const int4*)(mk + e);
            const int4 x1 = *(const int4*)(mk + e + 4);
            unsigned bv = (unsigned)(x0.x != 0)        | ((unsigned)(x0.y != 0) << 1)
                        | ((unsigned)(x0.z != 0) << 2) | ((unsigned)(x0.w != 0) << 3)
                        | ((unsigned)(x1.x != 0) << 4) | ((unsigned)(x1.y != 0) << 5)
                        | ((unsigned)(x1.z != 0) << 6) | ((unsigned)(x1.w != 0) << 7);
            mp[e >> 3] = (u8)bv;
        }
    }
}

// ---------------------------------------------------------------------------
// qkv_gemm — UNCHANGED from R14 (BK=64 stacked half-tiles).
// ---------------------------------------------------------------------------
__global__ __launch_bounds__(256, 3)
void qkv_gemm(const u16* __restrict__ Xq, const u16* __restrict__ Xk,
              const u16* __restrict__ Xv,
              const u16* __restrict__ Wq, const u16* __restrict__ Wk,
              const u16* __restrict__ Wv,
              u16* __restrict__ Yq, u16* __restrict__ Yk, u16* __restrict__ Yv)
{
    __shared__ u16 As[2 * 128 * 32];    // [kk][row][col]
    __shared__ u16 Bs[2 * 128 * 32];

    const int z = blockIdx.z;
    const u16* X = (z == 0) ? Xq : (z == 1) ? Xk : Xv;
    const u16* W = (z == 0) ? Wq : (z == 1) ? Wk : Wv;
    u16*       Y = (z == 0) ? Yq : (z == 1) ? Yk : Yv;
    const float osc = (z == 0) ? 0.125f : 1.0f;

    const int tid  = threadIdx.x;
    const int lane = tid & 63;
    const int w    = tid >> 6;
    const int quad = lane >> 4;
    const int lq   = lane & 15;
    const int wm   = (w & 1) << 6;
    const int wn   = (w >> 1) << 6;

    const int m0 = blockIdx.x << 7;
    const int n0 = blockIdx.y << 7;

    const int srow = tid >> 2;
    const int scol = (tid & 3) << 3;
    const u16* ga0 = X + (size_t)(m0 + srow) * D_ + scol;
    const u16* ga1 = ga0 + (size_t)64 * D_;
    const u16* gb0 = W + (size_t)(n0 + srow) * D_ + scol;
    const u16* gb1 = gb0 + (size_t)64 * D_;

    u16* la0 = As + (size_t)w * 512;
    u16* la1 = As + 2048 + (size_t)w * 512;
    u16* lb0 = Bs + (size_t)w * 512;
    u16* lb1 = Bs + 2048 + (size_t)w * 512;

    f32x4 acc[4][4];
#pragma unroll
    for (int i = 0; i < 4; ++i)
#pragma unroll
        for (int j = 0; j < 4; ++j) acc[i][j] = (f32x4){0.f, 0.f, 0.f, 0.f};

    for (int kt = 0; kt < D_; kt += 64) {
        __syncthreads();
        gl_lds16(ga0 + kt, la0);
        gl_lds16(ga1 + kt, la1);
        gl_lds16(gb0 + kt, lb0);
        gl_lds16(gb1 + kt, lb1);
        gl_lds16(ga0 + kt + 32, la0 + 4096);
        gl_lds16(ga1 + kt + 32, la1 + 4096);
        gl_lds16(gb0 + kt + 32, lb0 + 4096);
        gl_lds16(gb1 + kt + 32, lb1 + 4096);
        __syncthreads();

#pragma unroll
        for (int kk = 0; kk < 2; ++kk) {
            bf16x8 af[4], bf[4];
#pragma unroll
            for (int t = 0; t < 4; ++t) {
                af[t] = *(const bf16x8*)&As[(kk << 12) + (size_t)(wm + (t << 4) + lq) * 32 + (quad << 3)];
                bf[t] = *(const bf16x8*)&Bs[(kk << 12) + (size_t)(wn + (t << 4) + lq) * 32 + (quad << 3)];
            }
#pragma unroll
            for (int i = 0; i < 4; ++i)
#pragma unroll
                for (int j = 0; j < 4; ++j)
                    acc[i][j] = __builtin_amdgcn_mfma_f32_16x16x32_bf16(
                        af[i], bf[j], acc[i][j], 0, 0, 0);
        }
    }

#pragma unroll
    for (int i = 0; i < 4; ++i)
#pragma unroll
        for (int j = 0; j < 4; ++j)
#pragma unroll
            for (int r = 0; r < 4; ++r) {
                const int grow = m0 + wm + (i << 4) + (quad << 2) + r;
                const int of   = n0 + wn + (j << 4) + lq;
                const int b = grow >> 11, s = grow & (S_ - 1);
                const int h = of >> 6,    dk = of & 63;
                Y[(((size_t)(b * H_ + h)) * S_ + s) * DK_ + dk] =
                    f2bf(acc[i][j][r] * osc);
            }
}

// ---------------------------------------------------------------------------
// out_gemm — UNCHANGED from R14 (64x64 tile, BK=64).
// ---------------------------------------------------------------------------
__global__ __launch_bounds__(256, 4)
void out_gemm(const u16* __restrict__ X, const u16* __restrict__ W,
              float* __restrict__ Y)
{
    __shared__ u16 As[2 * 64 * 32];
    __shared__ u16 Bs[2 * 64 * 32];

    const int tid  = threadIdx.x;
    const int lane = tid & 63;
    const int w    = tid >> 6;
    const int quad = lane >> 4;
    const int lq   = lane & 15;
    const int wm   = (w & 1) << 5;
    const int wn   = (w >> 1) << 5;

    const int m0 = blockIdx.x << 6;
    const int n0 = blockIdx.y << 6;

    const int srow = tid >> 2;          // 0..63
    const int scol = (tid & 3) << 3;
    const u16* ga0 = X + (size_t)(m0 + srow) * D_ + scol;
    const u16* gb0 = W + (size_t)(n0 + srow) * D_ + scol;

    u16* la0 = As + (size_t)w * 512;
    u16* lb0 = Bs + (size_t)w * 512;

    f32x4 acc[2][2];
#pragma unroll
    for (int i = 0; i < 2; ++i)
#pragma unroll
        for (int j = 0; j < 2; ++j) acc[i][j] = (f32x4){0.f, 0.f, 0.f, 0.f};

    for (int kt = 0; kt < D_; kt += 64) {
        __syncthreads();
        gl_lds16(ga0 + kt, la0);
        gl_lds16(gb0 + kt, lb0);
        gl_lds16(ga0 + kt + 32, la0 + 2048);
        gl_lds16(gb0 + kt + 32, lb0 + 2048);
        __syncthreads();

#pragma unroll
        for (int kk = 0; kk < 2; ++kk) {
            bf16x8 af[2], bf[2];
#pragma unroll
            for (int t = 0; t < 2; ++t) {
                af[t] = *(const bf16x8*)&As[(kk << 11) + (size_t)(wm + (t << 4) + lq) * 32 + (quad << 3)];
                bf[t] = *(const bf16x8*)&Bs[(kk << 11) + (size_t)(wn + (t << 4) + lq) * 32 + (quad << 3)];
            }
#pragma unroll
            for (int i = 0; i < 2; ++i)
#pragma unroll
                for (int j = 0; j < 2; ++j)
                    acc[i][j] = __builtin_amdgcn_mfma_f32_16x16x32_bf16(
                        af[i], bf[j], acc[i][j], 0, 0, 0);
        }
    }

#pragma unroll
    for (int i = 0; i < 2; ++i)
#pragma unroll
        for (int j = 0; j < 2; ++j)
#pragma unroll
            for (int r = 0; r < 4; ++r) {
                const int grow = m0 + wm + (i << 4) + (quad << 2) + r;
                const int gcol = n0 + wn + (j << 4) + lq;
                Y[(size_t)grow * D_ + gcol] = acc[i][j][r];
            }
}

// ---------------------------------------------------------------------------
// attn_mfma10 (R16): R14's proven per-wave shape (4 waves x 32 q-rows, same
// staging maps, same mask/exp/cvt_pk -> bit-identical p) with the KEY RANGE
// split across 2 blocks (1024 keys each, 16 chunks). Total LDS frag traffic
// unchanged (half chunks x double blocks) -- unlike R13/R15 which doubled it.
// Qs dropped (aQ direct from global, R13/R15-proven) -> LDS 36.9 KB -> 4
// blocks/CU at 4 independent barrier phases. Blocks emit f32 O / lsum
// partials; combine2 reassociates (one fp32 add point, ~1 ulp). setprio kept.
// ---------------------------------------------------------------------------
constexpr int AP = 72;

__global__ __launch_bounds__(256, 4)
void attn_mfma10(const u16* __restrict__ qb, const u16* __restrict__ kb,
                 const u16* __restrict__ vb, const u8* __restrict__ mpk,
                 float* __restrict__ opA, float* __restrict__ opB,
                 float* __restrict__ lsA, float* __restrict__ lsB)
{
    __shared__ __align__(16) u16 Ks[64][AP];
    __shared__ __align__(16) u16 Vt[64][AP];     // [d][pi(key)]
    __shared__ __align__(16) u16 Ps[128][AP];    // [q][pi(key)]

    const int tid  = threadIdx.x;
    const int lane = tid & 63;
    const int w    = tid >> 6;
    const int quad = lane >> 4;
    const int lq   = lane & 15;
    const int w32  = w << 5;

    // bijective XCD swizzle over 1024 blocks: XCD (bid&7) gets 128 contiguous
    // logical tiles = 4 (b,h) pairs' K/V (2 MB) in its L2.
    const int bid = (int)(blockIdx.x + gridDim.x * (blockIdx.y + gridDim.y * blockIdx.z));
    const int swz = (bid & 7) * 128 + (bid >> 3);       // nwg = 1024
    const int ks = swz & 1;                // key-half
    const int q0 = ((swz >> 1) & 15) << 7;
    const int h  = (swz >> 5) & 15;
    const int b  = swz >> 9;

    const u16* qbh = qb + (((size_t)b * H_ + h) * S_ + q0) * DK_;
    const u16* kbh = kb + (((size_t)b * H_ + h) * S_ + (ks << 10)) * DK_;
    const u16* vbh = vb + (((size_t)b * H_ + h) * S_ + (ks << 10)) * DK_;

    // Q fragments direct from global (one-time, L2-resident)
    bf16x8 aQ[2][2];
#pragma unroll
    for (int i = 0; i < 2; ++i) {
        const size_t qr = (size_t)(w32 + (i << 4) + lq) * DK_;
        aQ[i][0] = *(const bf16x8*)&qbh[qr + (quad << 3)];
        aQ[i][1] = *(const bf16x8*)&qbh[qr + 32 + (quad << 3)];
    }

    f32x4 O[2][4];
    float lsum[2][4];
#pragma unroll
    for (int i = 0; i < 2; ++i)
#pragma unroll
        for (int t = 0; t < 4; ++t) O[i][t] = (f32x4){0.f, 0.f, 0.f, 0.f};
#pragma unroll
    for (int i = 0; i < 2; ++i)
#pragma unroll
        for (int r = 0; r < 4; ++r) lsum[i][r] = 0.f;

    // K staging map (R14)
    const int ksr = tid >> 2, ksc = (tid & 3) << 4;
    // V staging map (R14 pair map)
    const int vc  = tid & 15;
    const int vs  = (tid >> 4) & 1;
    const int vk0 = vc + (vs << 5);
    const int vdg = tid >> 5;
    const int vcol = (vc << 2) + (vs << 1);

    uint4 kr0, kr1, vr0, vr1;
    {
        kr0 = *(const uint4*)&kbh[(size_t)ksr * DK_ + ksc];
        kr1 = *(const uint4*)&kbh[(size_t)ksr * DK_ + ksc + 8];
        vr0 = *(const uint4*)&vbh[(size_t)vk0 * DK_ + (vdg << 3)];
        vr1 = *(const uint4*)&vbh[(size_t)(vk0 + 16) * DK_ + (vdg << 3)];
    }

    const int qrow0 = q0 + w32 + (quad << 2);
    const u8* mrow = mpk + (size_t)b * S_ * (S_ / 8) + (size_t)qrow0 * (S_ / 8)
                   + (ks << 7);

    for (int k0 = 0; k0 < 1024; k0 += 64) {
        u64 mw[2][4];
#pragma unroll
        for (int i = 0; i < 2; ++i)
#pragma unroll
            for (int r = 0; r < 4; ++r)
                mw[i][r] = *(const u64*)&mrow[(size_t)((i << 4) + r) * (S_ / 8) + (k0 >> 3)];

        __syncthreads();
        {   // staged regs -> LDS
            *(uint4*)&Ks[ksr][ksc]     = kr0;
            *(uint4*)&Ks[ksr][ksc + 8] = kr1;
            const u16* a0 = (const u16*)&vr0;
            const u16* a1 = (const u16*)&vr1;
#pragma unroll
            for (int i = 0; i < 8; ++i)
                *(ushort2*)&Vt[(vdg << 3) + i][vcol] = (ushort2){a0[i], a1[i]};
        }
        __syncthreads();

        if (k0 + 64 < 1024) {   // prefetch next chunk
            const size_t kb0 = (size_t)(k0 + 64 + ksr) * DK_ + ksc;
            kr0 = *(const uint4*)&kbh[kb0];
            kr1 = *(const uint4*)&kbh[kb0 + 8];
            const size_t vb0 = (size_t)(k0 + 64 + vk0) * DK_ + (vdg << 3);
            vr0 = *(const uint4*)&vbh[vb0];
            vr1 = *(const uint4*)&vbh[vb0 + (size_t)16 * DK_];
        }

        // ---- S = Q K^T : K frags shared across both row-groups ----
        f32x4 st[2][4];
        __builtin_amdgcn_s_setprio(1);
#pragma unroll
        for (int t = 0; t < 4; ++t) {
            const bf16x8 b0 = *(const bf16x8*)&Ks[(t << 4) + lq][quad << 3];
            const bf16x8 b1 = *(const bf16x8*)&Ks[(t << 4) + lq][32 + (quad << 3)];
#pragma unroll
            for (int i = 0; i < 2; ++i) {
                f32x4 c = {0.f, 0.f, 0.f, 0.f};
                c = __builtin_amdgcn_mfma_f32_16x16x32_bf16(aQ[i][0], b0, c, 0, 0, 0);
                c = __builtin_amdgcn_mfma_f32_16x16x32_bf16(aQ[i][1], b1, c, 0, 0, 0);
                st[i][t] = c;
            }
        }
        __builtin_amdgcn_s_setprio(0);

        // ---- exp (fixed base), masked selects, l partials, P pack ----
#pragma unroll
        for (int i = 0; i < 2; ++i)
#pragma unroll
            for (int r = 0; r < 4; ++r) {
                const unsigned lo = (unsigned)mw[i][r];
                const unsigned hi = (unsigned)(mw[i][r] >> 32);
                float p0 = __expf(st[i][0][r]);
                float p1 = __expf(st[i][1][r]);
                float p2 = __expf(st[i][2][r]);
                float p3 = __expf(st[i][3][r]);
                p0 = ((lo >> lq) & 1u) ? p0 : 1.0f;
                p1 = ((lo >> (lq + 16)) & 1u) ? p1 : 1.0f;
                p2 = ((hi >> lq) & 1u) ? p2 : 1.0f;
                p3 = ((hi >> (lq + 16)) & 1u) ? p3 : 1.0f;
                lsum[i][r] += (p0 + p1) + (p2 + p3);
                uint2 pw;
                pw.x = cvt_pk_bf16(p0, p1);
                pw.y = cvt_pk_bf16(p2, p3);
                *(uint2*)&Ps[w32 + (i << 4) + (quad << 2) + r][lq << 2] = pw;
            }

        // ---- O += P V (wave-local Ps rows: DS in-order, no barrier) ----
        bf16x8 aP[2][2];
#pragma unroll
        for (int i = 0; i < 2; ++i) {
            aP[i][0] = *(const bf16x8*)&Ps[w32 + (i << 4) + lq][quad << 3];
            aP[i][1] = *(const bf16x8*)&Ps[w32 + (i << 4) + lq][32 + (quad << 3)];
        }
        __builtin_amdgcn_s_setprio(1);
#pragma unroll
        for (int t = 0; t < 4; ++t) {
            const bf16x8 b0 = *(const bf16x8*)&Vt[(t << 4) + lq][quad << 3];
            const bf16x8 b1 = *(const bf16x8*)&Vt[(t << 4) + lq][32 + (quad << 3)];
#pragma unroll
            for (int i = 0; i < 2; ++i) {
                O[i][t] = __builtin_amdgcn_mfma_f32_16x16x32_bf16(aP[i][0], b0, O[i][t], 0, 0, 0);
                O[i][t] = __builtin_amdgcn_mfma_f32_16x16x32_bf16(aP[i][1], b1, O[i][t], 0, 0, 0);
            }
        }
        __builtin_amdgcn_s_setprio(0);
    }

    // 16-lane partial-l reduction (no inversion here; combine2 divides)
#pragma unroll
    for (int i = 0; i < 2; ++i)
#pragma unroll
        for (int r = 0; r < 4; ++r) {
#pragma unroll
            for (int off = 1; off < 16; off <<= 1)
                lsum[i][r] += __shfl_xor(lsum[i][r], off);
        }

    // write partials: op[(b*H+h)*S + row][d], ls[(b*H+h)*S + row]
    float* op = ks ? opB : opA;
    float* ls = ks ? lsB : lsA;
    const size_t rbase = ((size_t)b * H_ + h) * S_;
#pragma unroll
    for (int i = 0; i < 2; ++i)
#pragma unroll
        for (int t = 0; t < 4; ++t)
#pragma unroll
            for (int r = 0; r < 4; ++r) {
                const int row = qrow0 + (i << 4) + r;
                op[(rbase + row) * DK_ + (t << 4) + lq] = O[i][t][r];
            }
    if (lq == 0) {
#pragma unroll
        for (int i = 0; i < 2; ++i)
#pragma unroll
            for (int r = 0; r < 4; ++r)
                ls[rbase + qrow0 + (i << 4) + r] = lsum[i][r];
    }
}

// ---------------------------------------------------------------------------
// combine2 (R16): ctx = f2bf((Oa+Ob) / (la+lb)). Memory-bound, ~41 MB.
// Thread handles 8 consecutive d of one (b,h,s) row; scatters to ctx
// [b][s][h*64+d].
// ---------------------------------------------------------------------------
__global__ __launch_bounds__(256)
void combine2(const float* __restrict__ opA, const float* __restrict__ opB,
              const float* __restrict__ lsA, const float* __restrict__ lsB,
              u16* __restrict__ ctx)
{
    const size_t t = (size_t)blockIdx.x * 256 + threadIdx.x;   // 524288 threads
    const int row = (int)(t >> 3);          // (b*H+h)*S + s
    const int d0  = ((int)t & 7) << 3;
    const float linv = 1.0f / (lsA[row] + lsB[row]);

    const size_t base = (size_t)row * DK_ + d0;
    const float4 a0 = *(const float4*)(opA + base);
    const float4 a1 = *(const float4*)(opA + base + 4);
    const float4 b0 = *(const float4*)(opB + base);
    const float4 b1 = *(const float4*)(opB + base + 4);

    ushort4 o0, o1;
    o0.x = f2bf((a0.x + b0.x) * linv); o0.y = f2bf((a0.y + b0.y) * linv);
    o0.z = f2bf((a0.z + b0.z) * linv); o0.w = f2bf((a0.w + b0.w) * linv);
    o1.x = f2bf((a1.x + b1.x) * linv); o1.y = f2bf((a1.y + b1.y) * linv);
    o1.z = f2bf((a1.z + b1.z) * linv); o1.w = f2bf((a1.w + b1.w) * linv);

    const int bh = row >> 11, s = row & (S_ - 1);
    const int b  = bh >> 4,   h = bh & 15;
    u16* dst = ctx + ((size_t)b * S_ + s) * D_ + (h << 6) + d0;
    *(ushort4*)(dst)     = o0;
    *(ushort4*)(dst + 4) = o1;
}

// ---------------------------------------------------------------------------
// Workspace layout (u16 units), ~61 MB total (unchanged footprint):
//   [0)              xqb,xkb,xvb : 3*XBSZ  (bf16 X; dead after qkv_gemm)
//        attn partials alias the dead X region: opB (16 MB = xqb+xkb),
//        lsA/lsB (0.5 MB, into xvb region). opA aliases d_out (16 MB f32,
//        overwritten by out_gemm last).
//   [3*XBSZ)         wqb..wob    : 4*WBSZ  (bf16 W)
//   [3*XBSZ+4*WBSZ)  qw,kw,vw    : 3*QSZ
//   after that       mpk         : MPKB bytes (bit-packed mask)
//   cx aliases qw (Q is register-loaded at attn block start; fully dead
//   when combine2 runs; out_gemm reads cx=qw).
// ---------------------------------------------------------------------------
extern "C" void kernel_launch(void* const* d_in, const int* in_sizes, int n_in,
                              void* d_out, int out_size, void* d_ws, size_t ws_size,
                              hipStream_t stream)
{
    const float* Q    = (const float*)d_in[0];
    const float* K    = (const float*)d_in[1];
    const float* V    = (const float*)d_in[2];
    const int*   mask = (const int*)d_in[3];
    const float* Wq   = (const float*)d_in[4];
    const float* Wk   = (const float*)d_in[5];
    const float* Wv   = (const float*)d_in[6];
    const float* Wo   = (const float*)d_in[7];
    float* out = (float*)d_out;

    u16* xqb = (u16*)d_ws;
    u16* xkb = xqb + XBSZ;
    u16* xvb = xqb + 2 * XBSZ;
    u16* wqb = xqb + 3 * XBSZ;
    u16* wkb = wqb + WBSZ;
    u16* wvb = wqb + 2 * WBSZ;
    u16* wob = wqb + 3 * WBSZ;
    u16* qw  = wqb + 4 * WBSZ;
    u16* kw  = qw + QSZ;
    u16* vw  = qw + 2 * QSZ;
    u8*  mpk = (u8*)(qw + 3 * QSZ);

    // partial buffers over dead regions
    float* opA = out;                       // 16 MB (overwritten last by out_gemm)
    float* opB = (float*)xqb;               // 16 MB over dead xqb+xkb
    float* lsA = (float*)xvb;               // 0.25 MB
    float* lsB = lsA + NRH;                 // 0.25 MB
    u16*   cx  = qw;                        // ctx over dead Q-bf16

    hipLaunchKernelGGL(cvt7m, dim3(2048), dim3(256), 0, stream,
                       Q, K, V, Wq, Wk, Wv, Wo, mask,
                       xqb, xkb, xvb, wqb, wkb, wvb, wob, mpk);
    hipLaunchKernelGGL(qkv_gemm, dim3(NROW / 128, D_ / 128, 3), dim3(256), 0, stream,
                       xqb, xkb, xvb, wqb, wkb, wvb, qw, kw, vw);
    hipLaunchKernelGGL(attn_mfma10, dim3(32, H_, B_), dim3(256), 0, stream,
                       qw, kw, vw, mpk, opA, opB, lsA, lsB);
    hipLaunchKernelGGL(combine2, dim3((unsigned)(NRH * 8 / 256)), dim3(256), 0, stream,
                       opA, opB, lsA, lsB, cx);
    hipLaunchKernelGGL(out_gemm, dim3(NROW / 64, D_ / 64), dim3(256), 0, stream,
                       cx, wob, out);
}

// Round 8
// 252.914 us; speedup vs baseline: 1.2014x; 1.2014x over previous
//
#include <hip/hip_runtime.h>

typedef unsigned short u16;
typedef unsigned char  u8;
typedef unsigned long long u64;
typedef __attribute__((ext_vector_type(8))) short bf16x8;   // 8 bf16 in 4 VGPRs
typedef __attribute__((ext_vector_type(4))) float f32x4;

constexpr int B_  = 2;
constexpr int S_  = 2048;
constexpr int D_  = 1024;
constexpr int H_  = 16;
constexpr int DK_ = 64;
constexpr int NROW = B_ * S_;                           // 4096
constexpr size_t QSZ  = (size_t)B_ * H_ * S_ * DK_;     // 4194304 elems per buffer
constexpr size_t XBSZ = (size_t)NROW * D_;              // 4194304 (one X matrix)
constexpr size_t WBSZ = (size_t)D_ * D_;                // 1048576 (one W matrix)
constexpr size_t MSZ  = (size_t)B_ * S_ * S_;           // 8388608 mask elems
constexpr size_t MPKB = MSZ / 8;                        // 1 MiB packed mask bytes
constexpr size_t NRH  = (size_t)B_ * H_ * S_;           // 65536 (b,h,s) rows

__device__ __forceinline__ u16 f2bf(float f) {
    union { float f; unsigned u; } c; c.f = f;
    unsigned r = c.u + 0x7fffu + ((c.u >> 16) & 1u);    // RNE
    return (u16)(r >> 16);
}
__device__ __forceinline__ unsigned pack2(float a, float b) {
    return (unsigned)f2bf(a) | ((unsigned)f2bf(b) << 16);
}
// HW packed f32->bf16 RNE: bit-identical to f2bf for finite values.
__device__ __forceinline__ unsigned cvt_pk_bf16(float a, float b) {
    unsigned r;
    asm("v_cvt_pk_bf16_f32 %0, %1, %2" : "=v"(r) : "v"(a), "v"(b));
    return r;
}

// async global->LDS, 16B per lane; lds ptr must be wave-uniform base
__device__ __forceinline__ void gl_lds16(const u16* g, u16* l) {
    __builtin_amdgcn_global_load_lds(
        (const __attribute__((address_space(1))) void*)g,
        (__attribute__((address_space(3))) void*)l, 16, 0, 0);
}

// ---------------------------------------------------------------------------
// cvt7m — UNCHANGED from R11. fp32 -> bf16 RNE of X/W + mask bit-pack.
// ---------------------------------------------------------------------------
__global__ __launch_bounds__(256)
void cvt7m(const float* __restrict__ s0, const float* __restrict__ s1,
           const float* __restrict__ s2, const float* __restrict__ s3,
           const float* __restrict__ s4, const float* __restrict__ s5,
           const float* __restrict__ s6, const int* __restrict__ mk,
           u16* __restrict__ d0, u16* __restrict__ d1, u16* __restrict__ d2,
           u16* __restrict__ d3, u16* __restrict__ d4, u16* __restrict__ d5,
           u16* __restrict__ d6, u8* __restrict__ mp)
{
    constexpr size_t XT = 3 * XBSZ;                            // 12582912
    constexpr int NCF = (int)((3 * XBSZ + 4 * WBSZ) / 2048);   // 8192
    constexpr int NCM = (int)(MSZ / 2048);                     // 4096

    for (int c = blockIdx.x; c < NCF + NCM; c += gridDim.x) {
        if (c < NCF) {
            const size_t base = (size_t)c * 2048;
            const float* s; u16* d; size_t off;
            if (base < XT) {
                const int a = (int)(base >> 22);
                off = base & (XBSZ - 1);
                s = (a == 0) ? s0 : (a == 1) ? s1 : s2;
                d = (a == 0) ? d0 : (a == 1) ? d1 : d2;
            } else {
                const size_t r = base - XT;
                const int a = (int)(r >> 20);
                off = r & (WBSZ - 1);
                s = (a == 0) ? s3 : (a == 1) ? s4 : (a == 2) ? s5 : s6;
                d = (a == 0) ? d3 : (a == 1) ? d4 : (a == 2) ? d5 : d6;
            }
            const size_t e = off + (size_t)threadIdx.x * 8;
            const float4 x0 = *(const float4*)(s + e);
            const float4 x1 = *(const float4*)(s + e + 4);
            uint4 p;
            p.x = pack2(x0.x, x0.y); p.y = pack2(x0.z, x0.w);
            p.z = pack2(x1.x, x1.y); p.w = pack2(x1.z, x1.w);
            *(uint4*)(d + e) = p;
        } else {
            const size_t e = (size_t)(c - NCF) * 2048 + (size_t)threadIdx.x * 8;
            const int4 x0 = *(const int4*)(mk + e);
            const int4 x1 = *(const int4*)(mk + e + 4);
            unsigned bv = (unsigned)(x0.x != 0)        | ((unsigned)(x0.y != 0) << 1)
                        | ((unsigned)(x0.z != 0) << 2) | ((unsigned)(x0.w != 0) << 3)
                        | ((unsigned)(x1.x != 0) << 4) | ((unsigned)(x1.y != 0) << 5)
                        | ((unsigned)(x1.z != 0) << 6) | ((unsigned)(x1.w != 0) << 7);
            mp[e >> 3] = (u8)bv;
        }
    }
}

// ---------------------------------------------------------------------------
// qkv_gemm — UNCHANGED from R14 (BK=64 stacked half-tiles).
// ---------------------------------------------------------------------------
__global__ __launch_bounds__(256, 3)
void qkv_gemm(const u16* __restrict__ Xq, const u16* __restrict__ Xk,
              const u16* __restrict__ Xv,
              const u16* __restrict__ Wq, const u16* __restrict__ Wk,
              const u16* __restrict__ Wv,
              u16* __restrict__ Yq, u16* __restrict__ Yk, u16* __restrict__ Yv)
{
    __shared__ u16 As[2 * 128 * 32];    // [kk][row][col]
    __shared__ u16 Bs[2 * 128 * 32];

    const int z = blockIdx.z;
    const u16* X = (z == 0) ? Xq : (z == 1) ? Xk : Xv;
    const u16* W = (z == 0) ? Wq : (z == 1) ? Wk : Wv;
    u16*       Y = (z == 0) ? Yq : (z == 1) ? Yk : Yv;
    const float osc = (z == 0) ? 0.125f : 1.0f;

    const int tid  = threadIdx.x;
    const int lane = tid & 63;
    const int w    = tid >> 6;
    const int quad = lane >> 4;
    const int lq   = lane & 15;
    const int wm   = (w & 1) << 6;
    const int wn   = (w >> 1) << 6;

    const int m0 = blockIdx.x << 7;
    const int n0 = blockIdx.y << 7;

    const int srow = tid >> 2;
    const int scol = (tid & 3) << 3;
    const u16* ga0 = X + (size_t)(m0 + srow) * D_ + scol;
    const u16* ga1 = ga0 + (size_t)64 * D_;
    const u16* gb0 = W + (size_t)(n0 + srow) * D_ + scol;
    const u16* gb1 = gb0 + (size_t)64 * D_;

    u16* la0 = As + (size_t)w * 512;
    u16* la1 = As + 2048 + (size_t)w * 512;
    u16* lb0 = Bs + (size_t)w * 512;
    u16* lb1 = Bs + 2048 + (size_t)w * 512;

    f32x4 acc[4][4];
#pragma unroll
    for (int i = 0; i < 4; ++i)
#pragma unroll
        for (int j = 0; j < 4; ++j) acc[i][j] = (f32x4){0.f, 0.f, 0.f, 0.f};

    for (int kt = 0; kt < D_; kt += 64) {
        __syncthreads();
        gl_lds16(ga0 + kt, la0);
        gl_lds16(ga1 + kt, la1);
        gl_lds16(gb0 + kt, lb0);
        gl_lds16(gb1 + kt, lb1);
        gl_lds16(ga0 + kt + 32, la0 + 4096);
        gl_lds16(ga1 + kt + 32, la1 + 4096);
        gl_lds16(gb0 + kt + 32, lb0 + 4096);
        gl_lds16(gb1 + kt + 32, lb1 + 4096);
        __syncthreads();

#pragma unroll
        for (int kk = 0; kk < 2; ++kk) {
            bf16x8 af[4], bf[4];
#pragma unroll
            for (int t = 0; t < 4; ++t) {
                af[t] = *(const bf16x8*)&As[(kk << 12) + (size_t)(wm + (t << 4) + lq) * 32 + (quad << 3)];
                bf[t] = *(const bf16x8*)&Bs[(kk << 12) + (size_t)(wn + (t << 4) + lq) * 32 + (quad << 3)];
            }
#pragma unroll
            for (int i = 0; i < 4; ++i)
#pragma unroll
                for (int j = 0; j < 4; ++j)
                    acc[i][j] = __builtin_amdgcn_mfma_f32_16x16x32_bf16(
                        af[i], bf[j], acc[i][j], 0, 0, 0);
        }
    }

#pragma unroll
    for (int i = 0; i < 4; ++i)
#pragma unroll
        for (int j = 0; j < 4; ++j)
#pragma unroll
            for (int r = 0; r < 4; ++r) {
                const int grow = m0 + wm + (i << 4) + (quad << 2) + r;
                const int of   = n0 + wn + (j << 4) + lq;
                const int b = grow >> 11, s = grow & (S_ - 1);
                const int h = of >> 6,    dk = of & 63;
                Y[(((size_t)(b * H_ + h)) * S_ + s) * DK_ + dk] =
                    f2bf(acc[i][j][r] * osc);
            }
}

// ---------------------------------------------------------------------------
// out_gemm — UNCHANGED from R14 (64x64 tile, BK=64).
// ---------------------------------------------------------------------------
__global__ __launch_bounds__(256, 4)
void out_gemm(const u16* __restrict__ X, const u16* __restrict__ W,
              float* __restrict__ Y)
{
    __shared__ u16 As[2 * 64 * 32];
    __shared__ u16 Bs[2 * 64 * 32];

    const int tid  = threadIdx.x;
    const int lane = tid & 63;
    const int w    = tid >> 6;
    const int quad = lane >> 4;
    const int lq   = lane & 15;
    const int wm   = (w & 1) << 5;
    const int wn   = (w >> 1) << 5;

    const int m0 = blockIdx.x << 6;
    const int n0 = blockIdx.y << 6;

    const int srow = tid >> 2;          // 0..63
    const int scol = (tid & 3) << 3;
    const u16* ga0 = X + (size_t)(m0 + srow) * D_ + scol;
    const u16* gb0 = W + (size_t)(n0 + srow) * D_ + scol;

    u16* la0 = As + (size_t)w * 512;
    u16* lb0 = Bs + (size_t)w * 512;

    f32x4 acc[2][2];
#pragma unroll
    for (int i = 0; i < 2; ++i)
#pragma unroll
        for (int j = 0; j < 2; ++j) acc[i][j] = (f32x4){0.f, 0.f, 0.f, 0.f};

    for (int kt = 0; kt < D_; kt += 64) {
        __syncthreads();
        gl_lds16(ga0 + kt, la0);
        gl_lds16(gb0 + kt, lb0);
        gl_lds16(ga0 + kt + 32, la0 + 2048);
        gl_lds16(gb0 + kt + 32, lb0 + 2048);
        __syncthreads();

#pragma unroll
        for (int kk = 0; kk < 2; ++kk) {
            bf16x8 af[2], bf[2];
#pragma unroll
            for (int t = 0; t < 2; ++t) {
                af[t] = *(const bf16x8*)&As[(kk << 11) + (size_t)(wm + (t << 4) + lq) * 32 + (quad << 3)];
                bf[t] = *(const bf16x8*)&Bs[(kk << 11) + (size_t)(wn + (t << 4) + lq) * 32 + (quad << 3)];
            }
#pragma unroll
            for (int i = 0; i < 2; ++i)
#pragma unroll
                for (int j = 0; j < 2; ++j)
                    acc[i][j] = __builtin_amdgcn_mfma_f32_16x16x32_bf16(
                        af[i], bf[j], acc[i][j], 0, 0, 0);
        }
    }

#pragma unroll
    for (int i = 0; i < 2; ++i)
#pragma unroll
        for (int j = 0; j < 2; ++j)
#pragma unroll
            for (int r = 0; r < 4; ++r) {
                const int grow = m0 + wm + (i << 4) + (quad << 2) + r;
                const int gcol = n0 + wn + (j << 4) + lq;
                Y[(size_t)grow * D_ + gcol] = acc[i][j][r];
            }
}

// ---------------------------------------------------------------------------
// attn_mfma10 (R17): R16 structure (K-split across 2 blocks, 32 rows/wave,
// traffic-neutral, partials + combine2) with the spill fixed:
//  (a) __launch_bounds__(256,3): cap ~170 VGPR. (256,4)'s 128-cap collapsed
//      the allocator to 64+spill twice (R12/R16); (256,2) allocs 88 for this
//      shape (R14). At ~88-110 alloc, VGPR allows 4 waves/SIMD; LDS (36.9KB)
//      allows 4 blocks/CU -> 2x R14 occupancy with unchanged DS traffic.
//  (b) mask-word loads moved AFTER the QK^T cluster: shortens their 16-VGPR
//      lifetime (they previously spanned barrier+staging+MFMA).
// Math/order byte-identical to R16 (passed, absmax unchanged).
// ---------------------------------------------------------------------------
constexpr int AP = 72;

__global__ __launch_bounds__(256, 3)
void attn_mfma10(const u16* __restrict__ qb, const u16* __restrict__ kb,
                 const u16* __restrict__ vb, const u8* __restrict__ mpk,
                 float* __restrict__ opA, float* __restrict__ opB,
                 float* __restrict__ lsA, float* __restrict__ lsB)
{
    __shared__ __align__(16) u16 Ks[64][AP];
    __shared__ __align__(16) u16 Vt[64][AP];     // [d][pi(key)]
    __shared__ __align__(16) u16 Ps[128][AP];    // [q][pi(key)]

    const int tid  = threadIdx.x;
    const int lane = tid & 63;
    const int w    = tid >> 6;
    const int quad = lane >> 4;
    const int lq   = lane & 15;
    const int w32  = w << 5;

    // bijective XCD swizzle over 1024 blocks: XCD (bid&7) gets 128 contiguous
    // logical tiles = 4 (b,h) pairs' K/V (2 MB) in its L2.
    const int bid = (int)(blockIdx.x + gridDim.x * (blockIdx.y + gridDim.y * blockIdx.z));
    const int swz = (bid & 7) * 128 + (bid >> 3);       // nwg = 1024
    const int ks = swz & 1;                // key-half
    const int q0 = ((swz >> 1) & 15) << 7;
    const int h  = (swz >> 5) & 15;
    const int b  = swz >> 9;

    const u16* qbh = qb + (((size_t)b * H_ + h) * S_ + q0) * DK_;
    const u16* kbh = kb + (((size_t)b * H_ + h) * S_ + (ks << 10)) * DK_;
    const u16* vbh = vb + (((size_t)b * H_ + h) * S_ + (ks << 10)) * DK_;

    // Q fragments direct from global (one-time, L2-resident)
    bf16x8 aQ[2][2];
#pragma unroll
    for (int i = 0; i < 2; ++i) {
        const size_t qr = (size_t)(w32 + (i << 4) + lq) * DK_;
        aQ[i][0] = *(const bf16x8*)&qbh[qr + (quad << 3)];
        aQ[i][1] = *(const bf16x8*)&qbh[qr + 32 + (quad << 3)];
    }

    f32x4 O[2][4];
    float lsum[2][4];
#pragma unroll
    for (int i = 0; i < 2; ++i)
#pragma unroll
        for (int t = 0; t < 4; ++t) O[i][t] = (f32x4){0.f, 0.f, 0.f, 0.f};
#pragma unroll
    for (int i = 0; i < 2; ++i)
#pragma unroll
        for (int r = 0; r < 4; ++r) lsum[i][r] = 0.f;

    // K staging map (R14)
    const int ksr = tid >> 2, ksc = (tid & 3) << 4;
    // V staging map (R14 pair map)
    const int vc  = tid & 15;
    const int vs  = (tid >> 4) & 1;
    const int vk0 = vc + (vs << 5);
    const int vdg = tid >> 5;
    const int vcol = (vc << 2) + (vs << 1);

    uint4 kr0, kr1, vr0, vr1;
    {
        kr0 = *(const uint4*)&kbh[(size_t)ksr * DK_ + ksc];
        kr1 = *(const uint4*)&kbh[(size_t)ksr * DK_ + ksc + 8];
        vr0 = *(const uint4*)&vbh[(size_t)vk0 * DK_ + (vdg << 3)];
        vr1 = *(const uint4*)&vbh[(size_t)(vk0 + 16) * DK_ + (vdg << 3)];
    }

    const int qrow0 = q0 + w32 + (quad << 2);
    const u8* mrow = mpk + (size_t)b * S_ * (S_ / 8) + (size_t)qrow0 * (S_ / 8)
                   + (ks << 7);

    for (int k0 = 0; k0 < 1024; k0 += 64) {
        __syncthreads();
        {   // staged regs -> LDS
            *(uint4*)&Ks[ksr][ksc]     = kr0;
            *(uint4*)&Ks[ksr][ksc + 8] = kr1;
            const u16* a0 = (const u16*)&vr0;
            const u16* a1 = (const u16*)&vr1;
#pragma unroll
            for (int i = 0; i < 8; ++i)
                *(ushort2*)&Vt[(vdg << 3) + i][vcol] = (ushort2){a0[i], a1[i]};
        }
        __syncthreads();

        if (k0 + 64 < 1024) {   // prefetch next chunk
            const size_t kb0 = (size_t)(k0 + 64 + ksr) * DK_ + ksc;
            kr0 = *(const uint4*)&kbh[kb0];
            kr1 = *(const uint4*)&kbh[kb0 + 8];
            const size_t vb0 = (size_t)(k0 + 64 + vk0) * DK_ + (vdg << 3);
            vr0 = *(const uint4*)&vbh[vb0];
            vr1 = *(const uint4*)&vbh[vb0 + (size_t)16 * DK_];
        }

        // ---- S = Q K^T : K frags shared across both row-groups ----
        f32x4 st[2][4];
        __builtin_amdgcn_s_setprio(1);
#pragma unroll
        for (int t = 0; t < 4; ++t) {
            const bf16x8 b0 = *(const bf16x8*)&Ks[(t << 4) + lq][quad << 3];
            const bf16x8 b1 = *(const bf16x8*)&Ks[(t << 4) + lq][32 + (quad << 3)];
#pragma unroll
            for (int i = 0; i < 2; ++i) {
                f32x4 c = {0.f, 0.f, 0.f, 0.f};
                c = __builtin_amdgcn_mfma_f32_16x16x32_bf16(aQ[i][0], b0, c, 0, 0, 0);
                c = __builtin_amdgcn_mfma_f32_16x16x32_bf16(aQ[i][1], b1, c, 0, 0, 0);
                st[i][t] = c;
            }
        }
        __builtin_amdgcn_s_setprio(0);

        // ---- mask words (moved here: short lifetime, L2-hit) ----
        u64 mw[2][4];
#pragma unroll
        for (int i = 0; i < 2; ++i)
#pragma unroll
            for (int r = 0; r < 4; ++r)
                mw[i][r] = *(const u64*)&mrow[(size_t)((i << 4) + r) * (S_ / 8) + (k0 >> 3)];

        // ---- exp (fixed base), masked selects, l partials, P pack ----
#pragma unroll
        for (int i = 0; i < 2; ++i)
#pragma unroll
            for (int r = 0; r < 4; ++r) {
                const unsigned lo = (unsigned)mw[i][r];
                const unsigned hi = (unsigned)(mw[i][r] >> 32);
                float p0 = __expf(st[i][0][r]);
                float p1 = __expf(st[i][1][r]);
                float p2 = __expf(st[i][2][r]);
                float p3 = __expf(st[i][3][r]);
                p0 = ((lo >> lq) & 1u) ? p0 : 1.0f;
                p1 = ((lo >> (lq + 16)) & 1u) ? p1 : 1.0f;
                p2 = ((hi >> lq) & 1u) ? p2 : 1.0f;
                p3 = ((hi >> (lq + 16)) & 1u) ? p3 : 1.0f;
                lsum[i][r] += (p0 + p1) + (p2 + p3);
                uint2 pw;
                pw.x = cvt_pk_bf16(p0, p1);
                pw.y = cvt_pk_bf16(p2, p3);
                *(uint2*)&Ps[w32 + (i << 4) + (quad << 2) + r][lq << 2] = pw;
            }

        // ---- O += P V (wave-local Ps rows: DS in-order, no barrier) ----
        bf16x8 aP[2][2];
#pragma unroll
        for (int i = 0; i < 2; ++i) {
            aP[i][0] = *(const bf16x8*)&Ps[w32 + (i << 4) + lq][quad << 3];
            aP[i][1] = *(const bf16x8*)&Ps[w32 + (i << 4) + lq][32 + (quad << 3)];
        }
        __builtin_amdgcn_s_setprio(1);
#pragma unroll
        for (int t = 0; t < 4; ++t) {
            const bf16x8 b0 = *(const bf16x8*)&Vt[(t << 4) + lq][quad << 3];
            const bf16x8 b1 = *(const bf16x8*)&Vt[(t << 4) + lq][32 + (quad << 3)];
#pragma unroll
            for (int i = 0; i < 2; ++i) {
                O[i][t] = __builtin_amdgcn_mfma_f32_16x16x32_bf16(aP[i][0], b0, O[i][t], 0, 0, 0);
                O[i][t] = __builtin_amdgcn_mfma_f32_16x16x32_bf16(aP[i][1], b1, O[i][t], 0, 0, 0);
            }
        }
        __builtin_amdgcn_s_setprio(0);
    }

    // 16-lane partial-l reduction (no inversion here; combine2 divides)
#pragma unroll
    for (int i = 0; i < 2; ++i)
#pragma unroll
        for (int r = 0; r < 4; ++r) {
#pragma unroll
            for (int off = 1; off < 16; off <<= 1)
                lsum[i][r] += __shfl_xor(lsum[i][r], off);
        }

    // write partials: op[(b*H+h)*S + row][d], ls[(b*H+h)*S + row]
    float* op = ks ? opB : opA;
    float* ls = ks ? lsB : lsA;
    const size_t rbase = ((size_t)b * H_ + h) * S_;
#pragma unroll
    for (int i = 0; i < 2; ++i)
#pragma unroll
        for (int t = 0; t < 4; ++t)
#pragma unroll
            for (int r = 0; r < 4; ++r) {
                const int row = qrow0 + (i << 4) + r;
                op[(rbase + row) * DK_ + (t << 4) + lq] = O[i][t][r];
            }
    if (lq == 0) {
#pragma unroll
        for (int i = 0; i < 2; ++i)
#pragma unroll
            for (int r = 0; r < 4; ++r)
                ls[rbase + qrow0 + (i << 4) + r] = lsum[i][r];
    }
}

// ---------------------------------------------------------------------------
// combine2 — UNCHANGED from R16. ctx = f2bf((Oa+Ob) / (la+lb)).
// ---------------------------------------------------------------------------
__global__ __launch_bounds__(256)
void combine2(const float* __restrict__ opA, const float* __restrict__ opB,
              const float* __restrict__ lsA, const float* __restrict__ lsB,
              u16* __restrict__ ctx)
{
    const size_t t = (size_t)blockIdx.x * 256 + threadIdx.x;   // 524288 threads
    const int row = (int)(t >> 3);          // (b*H+h)*S + s
    const int d0  = ((int)t & 7) << 3;
    const float linv = 1.0f / (lsA[row] + lsB[row]);

    const size_t base = (size_t)row * DK_ + d0;
    const float4 a0 = *(const float4*)(opA + base);
    const float4 a1 = *(const float4*)(opA + base + 4);
    const float4 b0 = *(const float4*)(opB + base);
    const float4 b1 = *(const float4*)(opB + base + 4);

    ushort4 o0, o1;
    o0.x = f2bf((a0.x + b0.x) * linv); o0.y = f2bf((a0.y + b0.y) * linv);
    o0.z = f2bf((a0.z + b0.z) * linv); o0.w = f2bf((a0.w + b0.w) * linv);
    o1.x = f2bf((a1.x + b1.x) * linv); o1.y = f2bf((a1.y + b1.y) * linv);
    o1.z = f2bf((a1.z + b1.z) * linv); o1.w = f2bf((a1.w + b1.w) * linv);

    const int bh = row >> 11, s = row & (S_ - 1);
    const int b  = bh >> 4,   h = bh & 15;
    u16* dst = ctx + ((size_t)b * S_ + s) * D_ + (h << 6) + d0;
    *(ushort4*)(dst)     = o0;
    *(ushort4*)(dst + 4) = o1;
}

// ---------------------------------------------------------------------------
// Workspace layout (u16 units), ~61 MB total (unchanged footprint):
//   [0)              xqb,xkb,xvb : 3*XBSZ  (bf16 X; dead after qkv_gemm)
//        attn partials alias the dead X region: opB (16 MB = xqb+xkb),
//        lsA/lsB (0.5 MB, into xvb region). opA aliases d_out (16 MB f32,
//        overwritten by out_gemm last).
//   [3*XBSZ)         wqb..wob    : 4*WBSZ  (bf16 W)
//   [3*XBSZ+4*WBSZ)  qw,kw,vw    : 3*QSZ
//   after that       mpk         : MPKB bytes (bit-packed mask)
//   cx aliases qw (Q fully consumed when combine2 runs; out_gemm reads cx=qw).
// ---------------------------------------------------------------------------
extern "C" void kernel_launch(void* const* d_in, const int* in_sizes, int n_in,
                              void* d_out, int out_size, void* d_ws, size_t ws_size,
                              hipStream_t stream)
{
    const float* Q    = (const float*)d_in[0];
    const float* K    = (const float*)d_in[1];
    const float* V    = (const float*)d_in[2];
    const int*   mask = (const int*)d_in[3];
    const float* Wq   = (const float*)d_in[4];
    const float* Wk   = (const float*)d_in[5];
    const float* Wv   = (const float*)d_in[6];
    const float* Wo   = (const float*)d_in[7];
    float* out = (float*)d_out;

    u16* xqb = (u16*)d_ws;
    u16* xkb = xqb + XBSZ;
    u16* xvb = xqb + 2 * XBSZ;
    u16* wqb = xqb + 3 * XBSZ;
    u16* wkb = wqb + WBSZ;
    u16* wvb = wqb + 2 * WBSZ;
    u16* wob = wqb + 3 * WBSZ;
    u16* qw  = wqb + 4 * WBSZ;
    u16* kw  = qw + QSZ;
    u16* vw  = qw + 2 * QSZ;
    u8*  mpk = (u8*)(qw + 3 * QSZ);

    // partial buffers over dead regions
    float* opA = out;                       // 16 MB (overwritten last by out_gemm)
    float* opB = (float*)xqb;               // 16 MB over dead xqb+xkb
    float* lsA = (float*)xvb;               // 0.25 MB
    float* lsB = lsA + NRH;                 // 0.25 MB
    u16*   cx  = qw;                        // ctx over dead Q-bf16

    hipLaunchKernelGGL(cvt7m, dim3(2048), dim3(256), 0, stream,
                       Q, K, V, Wq, Wk, Wv, Wo, mask,
                       xqb, xkb, xvb, wqb, wkb, wvb, wob, mpk);
    hipLaunchKernelGGL(qkv_gemm, dim3(NROW / 128, D_ / 128, 3), dim3(256), 0, stream,
                       xqb, xkb, xvb, wqb, wkb, wvb, qw, kw, vw);
    hipLaunchKernelGGL(attn_mfma10, dim3(32, H_, B_), dim3(256), 0, stream,
                       qw, kw, vw, mpk, opA, opB, lsA, lsB);
    hipLaunchKernelGGL(combine2, dim3((unsigned)(NRH * 8 / 256)), dim3(256), 0, stream,
                       opA, opB, lsA, lsB, cx);
    hipLaunchKernelGGL(out_gemm, dim3(NROW / 64, D_ / 64), dim3(256), 0, stream,
                       cx, wob, out);
}

// Round 10
// 252.078 us; speedup vs baseline: 1.2053x; 1.0033x over previous
//
#include <hip/hip_runtime.h>

typedef unsigned short u16;
typedef unsigned char  u8;
typedef unsigned long long u64;
typedef __attribute__((ext_vector_type(8))) short bf16x8;   // 8 bf16 in 4 VGPRs
typedef __attribute__((ext_vector_type(4))) float f32x4;

constexpr int B_  = 2;
constexpr int S_  = 2048;
constexpr int D_  = 1024;
constexpr int H_  = 16;
constexpr int DK_ = 64;
constexpr int NROW = B_ * S_;                           // 4096
constexpr size_t QSZ  = (size_t)B_ * H_ * S_ * DK_;     // 4194304 elems per buffer
constexpr size_t XBSZ = (size_t)NROW * D_;              // 4194304 (one X matrix)
constexpr size_t WBSZ = (size_t)D_ * D_;                // 1048576 (one W matrix)
constexpr size_t MSZ  = (size_t)B_ * S_ * S_;           // 8388608 mask elems
constexpr size_t MPKB = MSZ / 8;                        // 1 MiB packed mask bytes

__device__ __forceinline__ u16 f2bf(float f) {
    union { float f; unsigned u; } c; c.f = f;
    unsigned r = c.u + 0x7fffu + ((c.u >> 16) & 1u);    // RNE
    return (u16)(r >> 16);
}
__device__ __forceinline__ unsigned pack2(float a, float b) {
    return (unsigned)f2bf(a) | ((unsigned)f2bf(b) << 16);
}
// HW packed f32->bf16 RNE: bit-identical to f2bf for finite values.
__device__ __forceinline__ unsigned cvt_pk_bf16(float a, float b) {
    unsigned r;
    asm("v_cvt_pk_bf16_f32 %0, %1, %2" : "=v"(r) : "v"(a), "v"(b));
    return r;
}

// async global->LDS, 16B per lane; lds ptr must be wave-uniform base
__device__ __forceinline__ void gl_lds16(const u16* g, u16* l) {
    __builtin_amdgcn_global_load_lds(
        (const __attribute__((address_space(1))) void*)g,
        (__attribute__((address_space(3))) void*)l, 16, 0, 0);
}

// ---------------------------------------------------------------------------
// cvt7m — UNCHANGED from R11. fp32 -> bf16 RNE of X/W + mask bit-pack.
// ---------------------------------------------------------------------------
__global__ __launch_bounds__(256)
void cvt7m(const float* __restrict__ s0, const float* __restrict__ s1,
           const float* __restrict__ s2, const float* __restrict__ s3,
           const float* __restrict__ s4, const float* __restrict__ s5,
           const float* __restrict__ s6, const int* __restrict__ mk,
           u16* __restrict__ d0, u16* __restrict__ d1, u16* __restrict__ d2,
           u16* __restrict__ d3, u16* __restrict__ d4, u16* __restrict__ d5,
           u16* __restrict__ d6, u8* __restrict__ mp)
{
    constexpr size_t XT = 3 * XBSZ;                            // 12582912
    constexpr int NCF = (int)((3 * XBSZ + 4 * WBSZ) / 2048);   // 8192
    constexpr int NCM = (int)(MSZ / 2048);                     // 4096

    for (int c = blockIdx.x; c < NCF + NCM; c += gridDim.x) {
        if (c < NCF) {
            const size_t base = (size_t)c * 2048;
            const float* s; u16* d; size_t off;
            if (base < XT) {
                const int a = (int)(base >> 22);
                off = base & (XBSZ - 1);
                s = (a == 0) ? s0 : (a == 1) ? s1 : s2;
                d = (a == 0) ? d0 : (a == 1) ? d1 : d2;
            } else {
                const size_t r = base - XT;
                const int a = (int)(r >> 20);
                off = r & (WBSZ - 1);
                s = (a == 0) ? s3 : (a == 1) ? s4 : (a == 2) ? s5 : s6;
                d = (a == 0) ? d3 : (a == 1) ? d4 : (a == 2) ? d5 : d6;
            }
            const size_t e = off + (size_t)threadIdx.x * 8;
            const float4 x0 = *(const float4*)(s + e);
            const float4 x1 = *(const float4*)(s + e + 4);
            uint4 p;
            p.x = pack2(x0.x, x0.y); p.y = pack2(x0.z, x0.w);
            p.z = pack2(x1.x, x1.y); p.w = pack2(x1.z, x1.w);
            *(uint4*)(d + e) = p;
        } else {
            const size_t e = (size_t)(c - NCF) * 2048 + (size_t)threadIdx.x * 8;
            const int4 x0 = *(const int4*)(mk + e);
            const int4 x1 = *(const int4*)(mk + e + 4);
            unsigned bv = (unsigned)(x0.x != 0)        | ((unsigned)(x0.y != 0) << 1)
                        | ((unsigned)(x0.z != 0) << 2) | ((unsigned)(x0.w != 0) << 3)
                        | ((unsigned)(x1.x != 0) << 4) | ((unsigned)(x1.y != 0) << 5)
                        | ((unsigned)(x1.z != 0) << 6) | ((unsigned)(x1.w != 0) << 7);
            mp[e >> 3] = (u8)bv;
        }
    }
}

// ---------------------------------------------------------------------------
// qkv_gemm (R18/R19): R14 BK=64 structure + bijective XCD swizzle of the
// (m,n) plane (256 tiles per z, 256%8==0). XCD c owns one full n-column: its
// W panel (128x1024 bf16 = 256 KB) stays L2-resident; X streams via L3 once.
// K order unchanged -> bit-exact.
// ---------------------------------------------------------------------------
__global__ __launch_bounds__(256, 3)
void qkv_gemm(const u16* __restrict__ Xq, const u16* __restrict__ Xk,
              const u16* __restrict__ Xv,
              const u16* __restrict__ Wq, const u16* __restrict__ Wk,
              const u16* __restrict__ Wv,
              u16* __restrict__ Yq, u16* __restrict__ Yk, u16* __restrict__ Yv)
{
    __shared__ u16 As[2 * 128 * 32];    // [kk][row][col]
    __shared__ u16 Bs[2 * 128 * 32];

    const int z = blockIdx.z;
    const u16* X = (z == 0) ? Xq : (z == 1) ? Xk : Xv;
    const u16* W = (z == 0) ? Wq : (z == 1) ? Wk : Wv;
    u16*       Y = (z == 0) ? Yq : (z == 1) ? Yk : Yv;
    const float osc = (z == 0) ? 0.125f : 1.0f;

    const int tid  = threadIdx.x;
    const int lane = tid & 63;
    const int w    = tid >> 6;
    const int quad = lane >> 4;
    const int lq   = lane & 15;
    const int wm   = (w & 1) << 6;
    const int wn   = (w >> 1) << 6;

    // XCD swizzle within the (m,n) plane: XCD (bid2&7) gets 32 contiguous
    // logical tiles = one full n-column (all 32 m-tiles for one n0).
    const int bid2 = (int)(blockIdx.x + (blockIdx.y << 5));      // 0..255
    const int swz2 = (bid2 & 7) * 32 + (bid2 >> 3);
    const int m0 = (swz2 & 31) << 7;
    const int n0 = (swz2 >> 5) << 7;

    const int srow = tid >> 2;
    const int scol = (tid & 3) << 3;
    const u16* ga0 = X + (size_t)(m0 + srow) * D_ + scol;
    const u16* ga1 = ga0 + (size_t)64 * D_;
    const u16* gb0 = W + (size_t)(n0 + srow) * D_ + scol;
    const u16* gb1 = gb0 + (size_t)64 * D_;

    u16* la0 = As + (size_t)w * 512;
    u16* la1 = As + 2048 + (size_t)w * 512;
    u16* lb0 = Bs + (size_t)w * 512;
    u16* lb1 = Bs + 2048 + (size_t)w * 512;

    f32x4 acc[4][4];
#pragma unroll
    for (int i = 0; i < 4; ++i)
#pragma unroll
        for (int j = 0; j < 4; ++j) acc[i][j] = (f32x4){0.f, 0.f, 0.f, 0.f};

    for (int kt = 0; kt < D_; kt += 64) {
        __syncthreads();
        gl_lds16(ga0 + kt, la0);
        gl_lds16(ga1 + kt, la1);
        gl_lds16(gb0 + kt, lb0);
        gl_lds16(gb1 + kt, lb1);
        gl_lds16(ga0 + kt + 32, la0 + 4096);
        gl_lds16(ga1 + kt + 32, la1 + 4096);
        gl_lds16(gb0 + kt + 32, lb0 + 4096);
        gl_lds16(gb1 + kt + 32, lb1 + 4096);
        __syncthreads();

#pragma unroll
        for (int kk = 0; kk < 2; ++kk) {
            bf16x8 af[4], bf[4];
#pragma unroll
            for (int t = 0; t < 4; ++t) {
                af[t] = *(const bf16x8*)&As[(kk << 12) + (size_t)(wm + (t << 4) + lq) * 32 + (quad << 3)];
                bf[t] = *(const bf16x8*)&Bs[(kk << 12) + (size_t)(wn + (t << 4) + lq) * 32 + (quad << 3)];
            }
#pragma unroll
            for (int i = 0; i < 4; ++i)
#pragma unroll
                for (int j = 0; j < 4; ++j)
                    acc[i][j] = __builtin_amdgcn_mfma_f32_16x16x32_bf16(
                        af[i], bf[j], acc[i][j], 0, 0, 0);
        }
    }

#pragma unroll
    for (int i = 0; i < 4; ++i)
#pragma unroll
        for (int j = 0; j < 4; ++j)
#pragma unroll
            for (int r = 0; r < 4; ++r) {
                const int grow = m0 + wm + (i << 4) + (quad << 2) + r;
                const int of   = n0 + wn + (j << 4) + lq;
                const int b = grow >> 11, s = grow & (S_ - 1);
                const int h = of >> 6,    dk = of & 63;
                Y[(((size_t)(b * H_ + h)) * S_ + s) * DK_ + dk] =
                    f2bf(acc[i][j][r] * osc);
            }
}

// ---------------------------------------------------------------------------
// out_gemm (R18/R19): R14 64x64 structure + bijective XCD swizzle (1024
// tiles). XCD c owns 128 contiguous logical tiles = two n-columns (two
// 128 KB W panels L2-resident). K order unchanged -> bit-exact.
// ---------------------------------------------------------------------------
__global__ __launch_bounds__(256, 4)
void out_gemm(const u16* __restrict__ X, const u16* __restrict__ W,
              float* __restrict__ Y)
{
    __shared__ u16 As[2 * 64 * 32];
    __shared__ u16 Bs[2 * 64 * 32];

    const int tid  = threadIdx.x;
    const int lane = tid & 63;
    const int w    = tid >> 6;
    const int quad = lane >> 4;
    const int lq   = lane & 15;
    const int wm   = (w & 1) << 5;
    const int wn   = (w >> 1) << 5;

    const int bid2 = (int)(blockIdx.x + (blockIdx.y << 6));      // 0..1023
    const int swz2 = (bid2 & 7) * 128 + (bid2 >> 3);
    const int m0 = (swz2 & 63) << 6;
    const int n0 = (swz2 >> 6) << 6;

    const int srow = tid >> 2;          // 0..63
    const int scol = (tid & 3) << 3;
    const u16* ga0 = X + (size_t)(m0 + srow) * D_ + scol;
    const u16* gb0 = W + (size_t)(n0 + srow) * D_ + scol;

    u16* la0 = As + (size_t)w * 512;
    u16* lb0 = Bs + (size_t)w * 512;

    f32x4 acc[2][2];
#pragma unroll
    for (int i = 0; i < 2; ++i)
#pragma unroll
        for (int j = 0; j < 2; ++j) acc[i][j] = (f32x4){0.f, 0.f, 0.f, 0.f};

    for (int kt = 0; kt < D_; kt += 64) {
        __syncthreads();
        gl_lds16(ga0 + kt, la0);
        gl_lds16(gb0 + kt, lb0);
        gl_lds16(ga0 + kt + 32, la0 + 2048);
        gl_lds16(gb0 + kt + 32, lb0 + 2048);
        __syncthreads();

#pragma unroll
        for (int kk = 0; kk < 2; ++kk) {
            bf16x8 af[2], bf[2];
#pragma unroll
            for (int t = 0; t < 2; ++t) {
                af[t] = *(const bf16x8*)&As[(kk << 11) + (size_t)(wm + (t << 4) + lq) * 32 + (quad << 3)];
                bf[t] = *(const bf16x8*)&Bs[(kk << 11) + (size_t)(wn + (t << 4) + lq) * 32 + (quad << 3)];
            }
#pragma unroll
            for (int i = 0; i < 2; ++i)
#pragma unroll
                for (int j = 0; j < 2; ++j)
                    acc[i][j] = __builtin_amdgcn_mfma_f32_16x16x32_bf16(
                        af[i], bf[j], acc[i][j], 0, 0, 0);
        }
    }

#pragma unroll
    for (int i = 0; i < 2; ++i)
#pragma unroll
        for (int j = 0; j < 2; ++j)
#pragma unroll
            for (int r = 0; r < 4; ++r) {
                const int grow = m0 + wm + (i << 4) + (quad << 2) + r;
                const int gcol = n0 + wn + (j << 4) + lq;
                Y[(size_t)grow * D_ + gcol] = acc[i][j][r];
            }
}

// ---------------------------------------------------------------------------
// attn_mfma8 — UNCHANGED from R14 (best measured attn: 69.7 us). QBLK=128,
// 4 waves, XCD swizzle, pair-mapped Vt staging, bit-packed mask, cvt_pk P.
// ---------------------------------------------------------------------------
constexpr int AP = 72;

__global__ __launch_bounds__(256, 2)
void attn_mfma8(const u16* __restrict__ qb, const u16* __restrict__ kb,
                const u16* __restrict__ vb, const u8* __restrict__ mpk,
                u16* __restrict__ ctx)
{
    __shared__ u16 Qs[128][AP];
    __shared__ u16 Ks[64][AP];
    __shared__ u16 Vt[64][AP];     // [d][pi(key)]
    __shared__ u16 Ps[128][AP];    // [q][pi(key)]

    const int tid  = threadIdx.x;
    const int lane = tid & 63;
    const int w    = tid >> 6;
    const int quad = lane >> 4;
    const int lq   = lane & 15;
    const int w32  = w << 5;

    const int bid = (int)(blockIdx.x + gridDim.x * (blockIdx.y + gridDim.y * blockIdx.z));
    const int swz = (bid & 7) * 64 + (bid >> 3);        // nwg = 512
    const int q0 = (swz & 15) << 7;
    const int h  = (swz >> 4) & 15;
    const int b  = swz >> 8;

    const u16* qbh = qb + (((size_t)b * H_ + h) * S_ + q0) * DK_;
    const u16* kbh = kb + ((size_t)b * H_ + h) * S_ * DK_;
    const u16* vbh = vb + ((size_t)b * H_ + h) * S_ * DK_;

    {   // stage Q tile [128][64]
        const int r = tid >> 1, c = (tid & 1) << 5;
#pragma unroll
        for (int u = 0; u < 4; ++u)
            *(uint4*)&Qs[r][c + (u << 3)] =
                *(const uint4*)&qbh[(size_t)r * DK_ + c + (u << 3)];
    }
    __syncthreads();
    bf16x8 aQ[2][2];
#pragma unroll
    for (int i = 0; i < 2; ++i) {
        aQ[i][0] = *(const bf16x8*)&Qs[w32 + (i << 4) + lq][quad << 3];
        aQ[i][1] = *(const bf16x8*)&Qs[w32 + (i << 4) + lq][32 + (quad << 3)];
    }

    f32x4 O[2][4];
    float lsum[2][4];
#pragma unroll
    for (int i = 0; i < 2; ++i)
#pragma unroll
        for (int t = 0; t < 4; ++t) O[i][t] = (f32x4){0.f, 0.f, 0.f, 0.f};
#pragma unroll
    for (int i = 0; i < 2; ++i)
#pragma unroll
        for (int r = 0; r < 4; ++r) lsum[i][r] = 0.f;

    // K staging map
    const int ksr = tid >> 2, ksc = (tid & 3) << 4;
    // V staging map: thread -> key-pair (vk0, vk0+16), 8 d's
    const int vc  = tid & 15;
    const int vs  = (tid >> 4) & 1;
    const int vk0 = vc + (vs << 5);
    const int vdg = tid >> 5;
    const int vcol = (vc << 2) + (vs << 1);

    uint4 kr0, kr1, vr0, vr1;
    {
        kr0 = *(const uint4*)&kbh[(size_t)ksr * DK_ + ksc];
        kr1 = *(const uint4*)&kbh[(size_t)ksr * DK_ + ksc + 8];
        vr0 = *(const uint4*)&vbh[(size_t)vk0 * DK_ + (vdg << 3)];
        vr1 = *(const uint4*)&vbh[(size_t)(vk0 + 16) * DK_ + (vdg << 3)];
    }

    const int qrow0 = q0 + w32 + (quad << 2);
    const u8* mrow = mpk + (size_t)b * S_ * (S_ / 8) + (size_t)qrow0 * (S_ / 8);

    for (int k0 = 0; k0 < S_; k0 += 64) {
        u64 mw[2][4];
#pragma unroll
        for (int i = 0; i < 2; ++i)
#pragma unroll
            for (int r = 0; r < 4; ++r)
                mw[i][r] = *(const u64*)&mrow[(size_t)((i << 4) + r) * (S_ / 8) + (k0 >> 3)];

        __syncthreads();
        {   // staged regs -> LDS
            *(uint4*)&Ks[ksr][ksc]     = kr0;
            *(uint4*)&Ks[ksr][ksc + 8] = kr1;
            const u16* a0 = (const u16*)&vr0;
            const u16* a1 = (const u16*)&vr1;
#pragma unroll
            for (int i = 0; i < 8; ++i)
                *(ushort2*)&Vt[(vdg << 3) + i][vcol] = (ushort2){a0[i], a1[i]};
        }
        __syncthreads();

        if (k0 + 64 < S_) {   // prefetch next chunk
            const size_t kb0 = (size_t)(k0 + 64 + ksr) * DK_ + ksc;
            kr0 = *(const uint4*)&kbh[kb0];
            kr1 = *(const uint4*)&kbh[kb0 + 8];
            const size_t vb0 = (size_t)(k0 + 64 + vk0) * DK_ + (vdg << 3);
            vr0 = *(const uint4*)&vbh[vb0];
            vr1 = *(const uint4*)&vbh[vb0 + (size_t)16 * DK_];
        }

        // ---- S = Q K^T : K frags shared across both row-groups ----
        f32x4 st[2][4];
#pragma unroll
        for (int t = 0; t < 4; ++t) {
            const bf16x8 b0 = *(const bf16x8*)&Ks[(t << 4) + lq][quad << 3];
            const bf16x8 b1 = *(const bf16x8*)&Ks[(t << 4) + lq][32 + (quad << 3)];
#pragma unroll
            for (int i = 0; i < 2; ++i) {
                f32x4 c = {0.f, 0.f, 0.f, 0.f};
                c = __builtin_amdgcn_mfma_f32_16x16x32_bf16(aQ[i][0], b0, c, 0, 0, 0);
                c = __builtin_amdgcn_mfma_f32_16x16x32_bf16(aQ[i][1], b1, c, 0, 0, 0);
                st[i][t] = c;
            }
        }

        // ---- exp (fixed base), masked selects, l partials, P pack ----
#pragma unroll
        for (int i = 0; i < 2; ++i)
#pragma unroll
            for (int r = 0; r < 4; ++r) {
                const unsigned lo = (unsigned)mw[i][r];
                const unsigned hi = (unsigned)(mw[i][r] >> 32);
                float p0 = __expf(st[i][0][r]);
                float p1 = __expf(st[i][1][r]);
                float p2 = __expf(st[i][2][r]);
                float p3 = __expf(st[i][3][r]);
                p0 = ((lo >> lq) & 1u) ? p0 : 1.0f;
                p1 = ((lo >> (lq + 16)) & 1u) ? p1 : 1.0f;
                p2 = ((hi >> lq) & 1u) ? p2 : 1.0f;
                p3 = ((hi >> (lq + 16)) & 1u) ? p3 : 1.0f;
                lsum[i][r] += (p0 + p1) + (p2 + p3);
                uint2 pw;
                pw.x = cvt_pk_bf16(p0, p1);
                pw.y = cvt_pk_bf16(p2, p3);
                *(uint2*)&Ps[w32 + (i << 4) + (quad << 2) + r][lq << 2] = pw;
            }

        // ---- O += P V (wave-local Ps rows: DS in-order, no barrier) ----
        bf16x8 aP[2][2];
#pragma unroll
        for (int i = 0; i < 2; ++i) {
            aP[i][0] = *(const bf16x8*)&Ps[w32 + (i << 4) + lq][quad << 3];
            aP[i][1] = *(const bf16x8*)&Ps[w32 + (i << 4) + lq][32 + (quad << 3)];
        }
#pragma unroll
        for (int t = 0; t < 4; ++t) {
            const bf16x8 b0 = *(const bf16x8*)&Vt[(t << 4) + lq][quad << 3];
            const bf16x8 b1 = *(const bf16x8*)&Vt[(t << 4) + lq][32 + (quad << 3)];
#pragma unroll
            for (int i = 0; i < 2; ++i) {
                O[i][t] = __builtin_amdgcn_mfma_f32_16x16x32_bf16(aP[i][0], b0, O[i][t], 0, 0, 0);
                O[i][t] = __builtin_amdgcn_mfma_f32_16x16x32_bf16(aP[i][1], b1, O[i][t], 0, 0, 0);
            }
        }
    }

    // deferred l reduction (16 lanes of the quad)
#pragma unroll
    for (int i = 0; i < 2; ++i)
#pragma unroll
        for (int r = 0; r < 4; ++r) {
#pragma unroll
            for (int off = 1; off < 16; off <<= 1)
                lsum[i][r] += __shfl_xor(lsum[i][r], off);
            lsum[i][r] = 1.0f / lsum[i][r];
        }

    // epilogue: bf16 ctx [b, s, h*64 + d]
#pragma unroll
    for (int i = 0; i < 2; ++i)
#pragma unroll
        for (int t = 0; t < 4; ++t)
#pragma unroll
            for (int r = 0; r < 4; ++r) {
                const int row = qrow0 + (i << 4) + r;
                ctx[((size_t)b * S_ + row) * D_ + (h << 6) + (t << 4) + lq] =
                    f2bf(O[i][t][r] * lsum[i][r]);
            }
}

// ---------------------------------------------------------------------------
// Workspace layout (u16 units), ~61 MB total (R14's):
//   [0)              xqb,xkb,xvb : 3*XBSZ  (bf16 X; dead after qkv_gemm)
//   [3*XBSZ)         wqb..wob    : 4*WBSZ  (bf16 W)
//   [3*XBSZ+4*WBSZ)  qw,kw,vw    : 3*QSZ
//   after that       mpk         : MPKB bytes (bit-packed mask)
//   cx aliases xqb (attn writes it after qkv_gemm's last read of xvb).
// ---------------------------------------------------------------------------
extern "C" void kernel_launch(void* const* d_in, const int* in_sizes, int n_in,
                              void* d_out, int out_size, void* d_ws, size_t ws_size,
                              hipStream_t stream)
{
    const float* Q    = (const float*)d_in[0];
    const float* K    = (const float*)d_in[1];
    const float* V    = (const float*)d_in[2];
    const int*   mask = (const int*)d_in[3];
    const float* Wq   = (const float*)d_in[4];
    const float* Wk   = (const float*)d_in[5];
    const float* Wv   = (const float*)d_in[6];
    const float* Wo   = (const float*)d_in[7];
    float* out = (float*)d_out;

    u16* xqb = (u16*)d_ws;
    u16* xkb = xqb + XBSZ;
    u16* xvb = xqb + 2 * XBSZ;
    u16* wqb = xqb + 3 * XBSZ;
    u16* wkb = wqb + WBSZ;
    u16* wvb = wqb + 2 * WBSZ;
    u16* wob = wqb + 3 * WBSZ;
    u16* qw  = wqb + 4 * WBSZ;
    u16* kw  = qw + QSZ;
    u16* vw  = qw + 2 * QSZ;
    u8*  mpk = (u8*)(qw + 3 * QSZ);
    u16* cx  = xqb;                 // alias: X-bf16 region is dead by then

    hipLaunchKernelGGL(cvt7m, dim3(2048), dim3(256), 0, stream,
                       Q, K, V, Wq, Wk, Wv, Wo, mask,
                       xqb, xkb, xvb, wqb, wkb, wvb, wob, mpk);
    hipLaunchKernelGGL(qkv_gemm, dim3(NROW / 128, D_ / 128, 3), dim3(256), 0, stream,
                       xqb, xkb, xvb, wqb, wkb, wvb, qw, kw, vw);
    hipLaunchKernelGGL(attn_mfma8, dim3(S_ / 128, H_, B_), dim3(256), 0, stream,
                       qw, kw, vw, mpk, cx);
    hipLaunchKernelGGL(out_gemm, dim3(NROW / 64, D_ / 64), dim3(256), 0, stream,
                       cx, wob, out);
}

// Round 11
// 251.191 us; speedup vs baseline: 1.2096x; 1.0035x over previous
//
#include <hip/hip_runtime.h>

typedef unsigned short u16;
typedef unsigned char  u8;
typedef unsigned long long u64;
typedef __attribute__((ext_vector_type(8))) short bf16x8;   // 8 bf16 in 4 VGPRs
typedef __attribute__((ext_vector_type(4))) float f32x4;

constexpr int B_  = 2;
constexpr int S_  = 2048;
constexpr int D_  = 1024;
constexpr int H_  = 16;
constexpr int DK_ = 64;
constexpr int NROW = B_ * S_;                           // 4096
constexpr size_t QSZ  = (size_t)B_ * H_ * S_ * DK_;     // 4194304 elems per buffer
constexpr size_t XBSZ = (size_t)NROW * D_;              // 4194304 (one X matrix)
constexpr size_t WBSZ = (size_t)D_ * D_;                // 1048576 (one W matrix)
constexpr size_t MSZ  = (size_t)B_ * S_ * S_;           // 8388608 mask elems
constexpr size_t MPKB = MSZ / 8;                        // 1 MiB packed mask bytes

__device__ __forceinline__ u16 f2bf(float f) {
    union { float f; unsigned u; } c; c.f = f;
    unsigned r = c.u + 0x7fffu + ((c.u >> 16) & 1u);    // RNE
    return (u16)(r >> 16);
}
__device__ __forceinline__ unsigned pack2(float a, float b) {
    return (unsigned)f2bf(a) | ((unsigned)f2bf(b) << 16);
}
// HW packed f32->bf16 RNE: bit-identical to f2bf for finite values.
__device__ __forceinline__ unsigned cvt_pk_bf16(float a, float b) {
    unsigned r;
    asm("v_cvt_pk_bf16_f32 %0, %1, %2" : "=v"(r) : "v"(a), "v"(b));
    return r;
}

// async global->LDS, 16B per lane; lds ptr must be wave-uniform base
__device__ __forceinline__ void gl_lds16(const u16* g, u16* l) {
    __builtin_amdgcn_global_load_lds(
        (const __attribute__((address_space(1))) void*)g,
        (__attribute__((address_space(3))) void*)l, 16, 0, 0);
}

// ---------------------------------------------------------------------------
// cvt7m — UNCHANGED from R11. fp32 -> bf16 RNE of X/W + mask bit-pack.
// ---------------------------------------------------------------------------
__global__ __launch_bounds__(256)
void cvt7m(const float* __restrict__ s0, const float* __restrict__ s1,
           const float* __restrict__ s2, const float* __restrict__ s3,
           const float* __restrict__ s4, const float* __restrict__ s5,
           const float* __restrict__ s6, const int* __restrict__ mk,
           u16* __restrict__ d0, u16* __restrict__ d1, u16* __restrict__ d2,
           u16* __restrict__ d3, u16* __restrict__ d4, u16* __restrict__ d5,
           u16* __restrict__ d6, u8* __restrict__ mp)
{
    constexpr size_t XT = 3 * XBSZ;                            // 12582912
    constexpr int NCF = (int)((3 * XBSZ + 4 * WBSZ) / 2048);   // 8192
    constexpr int NCM = (int)(MSZ / 2048);                     // 4096

    for (int c = blockIdx.x; c < NCF + NCM; c += gridDim.x) {
        if (c < NCF) {
            const size_t base = (size_t)c * 2048;
            const float* s; u16* d; size_t off;
            if (base < XT) {
                const int a = (int)(base >> 22);
                off = base & (XBSZ - 1);
                s = (a == 0) ? s0 : (a == 1) ? s1 : s2;
                d = (a == 0) ? d0 : (a == 1) ? d1 : d2;
            } else {
                const size_t r = base - XT;
                const int a = (int)(r >> 20);
                off = r & (WBSZ - 1);
                s = (a == 0) ? s3 : (a == 1) ? s4 : (a == 2) ? s5 : s6;
                d = (a == 0) ? d3 : (a == 1) ? d4 : (a == 2) ? d5 : d6;
            }
            const size_t e = off + (size_t)threadIdx.x * 8;
            const float4 x0 = *(const float4*)(s + e);
            const float4 x1 = *(const float4*)(s + e + 4);
            uint4 p;
            p.x = pack2(x0.x, x0.y); p.y = pack2(x0.z, x0.w);
            p.z = pack2(x1.x, x1.y); p.w = pack2(x1.z, x1.w);
            *(uint4*)(d + e) = p;
        } else {
            const size_t e = (size_t)(c - NCF) * 2048 + (size_t)threadIdx.x * 8;
            const int4 x0 = *(const int4*)(mk + e);
            const int4 x1 = *(const int4*)(mk + e + 4);
            unsigned bv = (unsigned)(x0.x != 0)        | ((unsigned)(x0.y != 0) << 1)
                        | ((unsigned)(x0.z != 0) << 2) | ((unsigned)(x0.w != 0) << 3)
                        | ((unsigned)(x1.x != 0) << 4) | ((unsigned)(x1.y != 0) << 5)
                        | ((unsigned)(x1.z != 0) << 6) | ((unsigned)(x1.w != 0) << 7);
            mp[e >> 3] = (u8)bv;
        }
    }
}

// ---------------------------------------------------------------------------
// qkv_gemm2 (R20): BK=32 LDS double-buffer, ONE barrier per K-step.
// Old: issue -> drain-barrier -> compute (full load latency exposed/iter).
// New: barrier(drains prev issue) -> issue(next -> buf^1) -> compute(buf).
// Loads overlap this wave's 16 MFMAs. Same 32 KB LDS, same K order -> bit-
// exact. XCD column swizzle kept (R19-verified).
// ---------------------------------------------------------------------------
__global__ __launch_bounds__(256, 3)
void qkv_gemm2(const u16* __restrict__ Xq, const u16* __restrict__ Xk,
               const u16* __restrict__ Xv,
               const u16* __restrict__ Wq, const u16* __restrict__ Wk,
               const u16* __restrict__ Wv,
               u16* __restrict__ Yq, u16* __restrict__ Yk, u16* __restrict__ Yv)
{
    __shared__ u16 As[2 * 128 * 32];    // [buf][row][col]
    __shared__ u16 Bs[2 * 128 * 32];

    const int z = blockIdx.z;
    const u16* X = (z == 0) ? Xq : (z == 1) ? Xk : Xv;
    const u16* W = (z == 0) ? Wq : (z == 1) ? Wk : Wv;
    u16*       Y = (z == 0) ? Yq : (z == 1) ? Yk : Yv;
    const float osc = (z == 0) ? 0.125f : 1.0f;

    const int tid  = threadIdx.x;
    const int lane = tid & 63;
    const int w    = tid >> 6;
    const int quad = lane >> 4;
    const int lq   = lane & 15;
    const int wm   = (w & 1) << 6;
    const int wn   = (w >> 1) << 6;

    const int bid2 = (int)(blockIdx.x + (blockIdx.y << 5));      // 0..255
    const int swz2 = (bid2 & 7) * 32 + (bid2 >> 3);
    const int m0 = (swz2 & 31) << 7;
    const int n0 = (swz2 >> 5) << 7;

    const int srow = tid >> 2;
    const int scol = (tid & 3) << 3;
    const u16* ga0 = X + (size_t)(m0 + srow) * D_ + scol;
    const u16* ga1 = ga0 + (size_t)64 * D_;
    const u16* gb0 = W + (size_t)(n0 + srow) * D_ + scol;
    const u16* gb1 = gb0 + (size_t)64 * D_;

    const int wof = w << 9;             // wave-uniform LDS offset (u16)

    f32x4 acc[4][4];
#pragma unroll
    for (int i = 0; i < 4; ++i)
#pragma unroll
        for (int j = 0; j < 4; ++j) acc[i][j] = (f32x4){0.f, 0.f, 0.f, 0.f};

    // prologue: issue chunk 0 into buf0
    gl_lds16(ga0, As + wof);
    gl_lds16(ga1, As + 2048 + wof);
    gl_lds16(gb0, Bs + wof);
    gl_lds16(gb1, Bs + 2048 + wof);

    for (int kt = 0; kt < D_; kt += 32) {
        const int bi = (kt >> 5) & 1;
        const int bo = bi << 12;                 // buffer offset (4096 u16)
        __syncthreads();                         // drains vmcnt: buf[bi] ready;
                                                 // prev iter's ds_reads done
        if (kt + 32 < D_) {                      // issue next chunk -> buf^1
            const int no = (bo ^ 4096);
            gl_lds16(ga0 + kt + 32, As + no + wof);
            gl_lds16(ga1 + kt + 32, As + no + 2048 + wof);
            gl_lds16(gb0 + kt + 32, Bs + no + wof);
            gl_lds16(gb1 + kt + 32, Bs + no + 2048 + wof);
        }

        bf16x8 af[4], bf[4];
#pragma unroll
        for (int t = 0; t < 4; ++t) {
            af[t] = *(const bf16x8*)&As[bo + (size_t)(wm + (t << 4) + lq) * 32 + (quad << 3)];
            bf[t] = *(const bf16x8*)&Bs[bo + (size_t)(wn + (t << 4) + lq) * 32 + (quad << 3)];
        }
#pragma unroll
        for (int i = 0; i < 4; ++i)
#pragma unroll
            for (int j = 0; j < 4; ++j)
                acc[i][j] = __builtin_amdgcn_mfma_f32_16x16x32_bf16(
                    af[i], bf[j], acc[i][j], 0, 0, 0);
    }

#pragma unroll
    for (int i = 0; i < 4; ++i)
#pragma unroll
        for (int j = 0; j < 4; ++j)
#pragma unroll
            for (int r = 0; r < 4; ++r) {
                const int grow = m0 + wm + (i << 4) + (quad << 2) + r;
                const int of   = n0 + wn + (j << 4) + lq;
                const int b = grow >> 11, s = grow & (S_ - 1);
                const int h = of >> 6,    dk = of & 63;
                Y[(((size_t)(b * H_ + h)) * S_ + s) * DK_ + dk] =
                    f2bf(acc[i][j][r] * osc);
            }
}

// ---------------------------------------------------------------------------
// out_gemm2 (R20): same single-barrier BK=32 double-buffer at 64x64 tile.
// 16 KB LDS, grid 1024 = 4 blocks/CU. XCD swizzle kept. Bit-exact.
// ---------------------------------------------------------------------------
__global__ __launch_bounds__(256, 4)
void out_gemm2(const u16* __restrict__ X, const u16* __restrict__ W,
               float* __restrict__ Y)
{
    __shared__ u16 As[2 * 64 * 32];
    __shared__ u16 Bs[2 * 64 * 32];

    const int tid  = threadIdx.x;
    const int lane = tid & 63;
    const int w    = tid >> 6;
    const int quad = lane >> 4;
    const int lq   = lane & 15;
    const int wm   = (w & 1) << 5;
    const int wn   = (w >> 1) << 5;

    const int bid2 = (int)(blockIdx.x + (blockIdx.y << 6));      // 0..1023
    const int swz2 = (bid2 & 7) * 128 + (bid2 >> 3);
    const int m0 = (swz2 & 63) << 6;
    const int n0 = (swz2 >> 6) << 6;

    const int srow = tid >> 2;          // 0..63
    const int scol = (tid & 3) << 3;
    const u16* ga0 = X + (size_t)(m0 + srow) * D_ + scol;
    const u16* gb0 = W + (size_t)(n0 + srow) * D_ + scol;

    const int wof = w << 9;

    f32x4 acc[2][2];
#pragma unroll
    for (int i = 0; i < 2; ++i)
#pragma unroll
        for (int j = 0; j < 2; ++j) acc[i][j] = (f32x4){0.f, 0.f, 0.f, 0.f};

    // prologue: issue chunk 0 into buf0
    gl_lds16(ga0, As + wof);
    gl_lds16(gb0, Bs + wof);

    for (int kt = 0; kt < D_; kt += 32) {
        const int bi = (kt >> 5) & 1;
        const int bo = bi << 11;                 // buffer offset (2048 u16)
        __syncthreads();
        if (kt + 32 < D_) {
            const int no = (bo ^ 2048);
            gl_lds16(ga0 + kt + 32, As + no + wof);
            gl_lds16(gb0 + kt + 32, Bs + no + wof);
        }

        bf16x8 af[2], bf[2];
#pragma unroll
        for (int t = 0; t < 2; ++t) {
            af[t] = *(const bf16x8*)&As[bo + (size_t)(wm + (t << 4) + lq) * 32 + (quad << 3)];
            bf[t] = *(const bf16x8*)&Bs[bo + (size_t)(wn + (t << 4) + lq) * 32 + (quad << 3)];
        }
#pragma unroll
        for (int i = 0; i < 2; ++i)
#pragma unroll
            for (int j = 0; j < 2; ++j)
                acc[i][j] = __builtin_amdgcn_mfma_f32_16x16x32_bf16(
                    af[i], bf[j], acc[i][j], 0, 0, 0);
    }

#pragma unroll
    for (int i = 0; i < 2; ++i)
#pragma unroll
        for (int j = 0; j < 2; ++j)
#pragma unroll
            for (int r = 0; r < 4; ++r) {
                const int grow = m0 + wm + (i << 4) + (quad << 2) + r;
                const int gcol = n0 + wn + (j << 4) + lq;
                Y[(size_t)grow * D_ + gcol] = acc[i][j][r];
            }
}

// ---------------------------------------------------------------------------
// attn_mfma11 (R20): R14 attn with K/V LDS DOUBLE-BUFFERED -> one barrier per
// chunk (was two). Per iter: write regs->buf[bi]; barrier; prefetch chunk+1
// regs; compute from buf[bi]. Hazard proof: write of buf[bi] at iter t+2
// follows barrier(t+1) which follows all reads at iter t. Ps aliases the
// dead Qs buffer (Qs only read in prologue; first Ps write is after the
// first loop barrier) -> LDS stays 55.3 KB, occupancy unchanged. Same
// values/order -> bit-identical output.
// ---------------------------------------------------------------------------
constexpr int AP = 72;

__global__ __launch_bounds__(256, 2)
void attn_mfma11(const u16* __restrict__ qb, const u16* __restrict__ kb,
                 const u16* __restrict__ vb, const u8* __restrict__ mpk,
                 u16* __restrict__ ctx)
{
    __shared__ u16 QPs[128][AP];        // Qs in prologue, Ps in loop
    __shared__ u16 Ks[2][64][AP];
    __shared__ u16 Vt[2][64][AP];       // [buf][d][pi(key)]

    const int tid  = threadIdx.x;
    const int lane = tid & 63;
    const int w    = tid >> 6;
    const int quad = lane >> 4;
    const int lq   = lane & 15;
    const int w32  = w << 5;

    const int bid = (int)(blockIdx.x + gridDim.x * (blockIdx.y + gridDim.y * blockIdx.z));
    const int swz = (bid & 7) * 64 + (bid >> 3);        // nwg = 512
    const int q0 = (swz & 15) << 7;
    const int h  = (swz >> 4) & 15;
    const int b  = swz >> 8;

    const u16* qbh = qb + (((size_t)b * H_ + h) * S_ + q0) * DK_;
    const u16* kbh = kb + ((size_t)b * H_ + h) * S_ * DK_;
    const u16* vbh = vb + ((size_t)b * H_ + h) * S_ * DK_;

    {   // stage Q tile [128][64] into QPs
        const int r = tid >> 1, c = (tid & 1) << 5;
#pragma unroll
        for (int u = 0; u < 4; ++u)
            *(uint4*)&QPs[r][c + (u << 3)] =
                *(const uint4*)&qbh[(size_t)r * DK_ + c + (u << 3)];
    }
    __syncthreads();
    bf16x8 aQ[2][2];
#pragma unroll
    for (int i = 0; i < 2; ++i) {
        aQ[i][0] = *(const bf16x8*)&QPs[w32 + (i << 4) + lq][quad << 3];
        aQ[i][1] = *(const bf16x8*)&QPs[w32 + (i << 4) + lq][32 + (quad << 3)];
    }

    f32x4 O[2][4];
    float lsum[2][4];
#pragma unroll
    for (int i = 0; i < 2; ++i)
#pragma unroll
        for (int t = 0; t < 4; ++t) O[i][t] = (f32x4){0.f, 0.f, 0.f, 0.f};
#pragma unroll
    for (int i = 0; i < 2; ++i)
#pragma unroll
        for (int r = 0; r < 4; ++r) lsum[i][r] = 0.f;

    // K staging map
    const int ksr = tid >> 2, ksc = (tid & 3) << 4;
    // V staging map: thread -> key-pair (vk0, vk0+16), 8 d's
    const int vc  = tid & 15;
    const int vs  = (tid >> 4) & 1;
    const int vk0 = vc + (vs << 5);
    const int vdg = tid >> 5;
    const int vcol = (vc << 2) + (vs << 1);

    uint4 kr0, kr1, vr0, vr1;
    {   // prologue: chunk 0 -> regs
        kr0 = *(const uint4*)&kbh[(size_t)ksr * DK_ + ksc];
        kr1 = *(const uint4*)&kbh[(size_t)ksr * DK_ + ksc + 8];
        vr0 = *(const uint4*)&vbh[(size_t)vk0 * DK_ + (vdg << 3)];
        vr1 = *(const uint4*)&vbh[(size_t)(vk0 + 16) * DK_ + (vdg << 3)];
    }

    const int qrow0 = q0 + w32 + (quad << 2);
    const u8* mrow = mpk + (size_t)b * S_ * (S_ / 8) + (size_t)qrow0 * (S_ / 8);

    for (int k0 = 0; k0 < S_; k0 += 64) {
        const int bi = (k0 >> 6) & 1;

        {   // (A) staged regs -> buf[bi]
            *(uint4*)&Ks[bi][ksr][ksc]     = kr0;
            *(uint4*)&Ks[bi][ksr][ksc + 8] = kr1;
            const u16* a0 = (const u16*)&vr0;
            const u16* a1 = (const u16*)&vr1;
#pragma unroll
            for (int i = 0; i < 8; ++i)
                *(ushort2*)&Vt[bi][(vdg << 3) + i][vcol] = (ushort2){a0[i], a1[i]};
        }
        __syncthreads();    // (B) single barrier per chunk

        if (k0 + 64 < S_) {   // (C) prefetch next chunk -> regs
            const size_t kb0 = (size_t)(k0 + 64 + ksr) * DK_ + ksc;
            kr0 = *(const uint4*)&kbh[kb0];
            kr1 = *(const uint4*)&kbh[kb0 + 8];
            const size_t vb0 = (size_t)(k0 + 64 + vk0) * DK_ + (vdg << 3);
            vr0 = *(const uint4*)&vbh[vb0];
            vr1 = *(const uint4*)&vbh[vb0 + (size_t)16 * DK_];
        }

        u64 mw[2][4];
#pragma unroll
        for (int i = 0; i < 2; ++i)
#pragma unroll
            for (int r = 0; r < 4; ++r)
                mw[i][r] = *(const u64*)&mrow[(size_t)((i << 4) + r) * (S_ / 8) + (k0 >> 3)];

        // ---- (D) S = Q K^T : K frags shared across both row-groups ----
        f32x4 st[2][4];
#pragma unroll
        for (int t = 0; t < 4; ++t) {
            const bf16x8 b0 = *(const bf16x8*)&Ks[bi][(t << 4) + lq][quad << 3];
            const bf16x8 b1 = *(const bf16x8*)&Ks[bi][(t << 4) + lq][32 + (quad << 3)];
#pragma unroll
            for (int i = 0; i < 2; ++i) {
                f32x4 c = {0.f, 0.f, 0.f, 0.f};
                c = __builtin_amdgcn_mfma_f32_16x16x32_bf16(aQ[i][0], b0, c, 0, 0, 0);
                c = __builtin_amdgcn_mfma_f32_16x16x32_bf16(aQ[i][1], b1, c, 0, 0, 0);
                st[i][t] = c;
            }
        }

        // ---- exp (fixed base), masked selects, l partials, P pack ----
#pragma unroll
        for (int i = 0; i < 2; ++i)
#pragma unroll
            for (int r = 0; r < 4; ++r) {
                const unsigned lo = (unsigned)mw[i][r];
                const unsigned hi = (unsigned)(mw[i][r] >> 32);
                float p0 = __expf(st[i][0][r]);
                float p1 = __expf(st[i][1][r]);
                float p2 = __expf(st[i][2][r]);
                float p3 = __expf(st[i][3][r]);
                p0 = ((lo >> lq) & 1u) ? p0 : 1.0f;
                p1 = ((lo >> (lq + 16)) & 1u) ? p1 : 1.0f;
                p2 = ((hi >> lq) & 1u) ? p2 : 1.0f;
                p3 = ((hi >> (lq + 16)) & 1u) ? p3 : 1.0f;
                lsum[i][r] += (p0 + p1) + (p2 + p3);
                uint2 pw;
                pw.x = cvt_pk_bf16(p0, p1);
                pw.y = cvt_pk_bf16(p2, p3);
                *(uint2*)&QPs[w32 + (i << 4) + (quad << 2) + r][lq << 2] = pw;
            }

        // ---- O += P V (wave-local rows: DS in-order, no barrier) ----
        bf16x8 aP[2][2];
#pragma unroll
        for (int i = 0; i < 2; ++i) {
            aP[i][0] = *(const bf16x8*)&QPs[w32 + (i << 4) + lq][quad << 3];
            aP[i][1] = *(const bf16x8*)&QPs[w32 + (i << 4) + lq][32 + (quad << 3)];
        }
#pragma unroll
        for (int t = 0; t < 4; ++t) {
            const bf16x8 b0 = *(const bf16x8*)&Vt[bi][(t << 4) + lq][quad << 3];
            const bf16x8 b1 = *(const bf16x8*)&Vt[bi][(t << 4) + lq][32 + (quad << 3)];
#pragma unroll
            for (int i = 0; i < 2; ++i) {
                O[i][t] = __builtin_amdgcn_mfma_f32_16x16x32_bf16(aP[i][0], b0, O[i][t], 0, 0, 0);
                O[i][t] = __builtin_amdgcn_mfma_f32_16x16x32_bf16(aP[i][1], b1, O[i][t], 0, 0, 0);
            }
        }
    }

    // deferred l reduction (16 lanes of the quad)
#pragma unroll
    for (int i = 0; i < 2; ++i)
#pragma unroll
        for (int r = 0; r < 4; ++r) {
#pragma unroll
            for (int off = 1; off < 16; off <<= 1)
                lsum[i][r] += __shfl_xor(lsum[i][r], off);
            lsum[i][r] = 1.0f / lsum[i][r];
        }

    // epilogue: bf16 ctx [b, s, h*64 + d]
#pragma unroll
    for (int i = 0; i < 2; ++i)
#pragma unroll
        for (int t = 0; t < 4; ++t)
#pragma unroll
            for (int r = 0; r < 4; ++r) {
                const int row = qrow0 + (i << 4) + r;
                ctx[((size_t)b * S_ + row) * D_ + (h << 6) + (t << 4) + lq] =
                    f2bf(O[i][t][r] * lsum[i][r]);
            }
}

// ---------------------------------------------------------------------------
// Workspace layout (u16 units), ~61 MB total (R14's):
//   [0)              xqb,xkb,xvb : 3*XBSZ  (bf16 X; dead after qkv_gemm)
//   [3*XBSZ)         wqb..wob    : 4*WBSZ  (bf16 W)
//   [3*XBSZ+4*WBSZ)  qw,kw,vw    : 3*QSZ
//   after that       mpk         : MPKB bytes (bit-packed mask)
//   cx aliases xqb (attn writes it after qkv_gemm's last read of xvb).
// ---------------------------------------------------------------------------
extern "C" void kernel_launch(void* const* d_in, const int* in_sizes, int n_in,
                              void* d_out, int out_size, void* d_ws, size_t ws_size,
                              hipStream_t stream)
{
    const float* Q    = (const float*)d_in[0];
    const float* K    = (const float*)d_in[1];
    const float* V    = (const float*)d_in[2];
    const int*   mask = (const int*)d_in[3];
    const float* Wq   = (const float*)d_in[4];
    const float* Wk   = (const float*)d_in[5];
    const float* Wv   = (const float*)d_in[6];
    const float* Wo   = (const float*)d_in[7];
    float* out = (float*)d_out;

    u16* xqb = (u16*)d_ws;
    u16* xkb = xqb + XBSZ;
    u16* xvb = xqb + 2 * XBSZ;
    u16* wqb = xqb + 3 * XBSZ;
    u16* wkb = wqb + WBSZ;
    u16* wvb = wqb + 2 * WBSZ;
    u16* wob = wqb + 3 * WBSZ;
    u16* qw  = wqb + 4 * WBSZ;
    u16* kw  = qw + QSZ;
    u16* vw  = qw + 2 * QSZ;
    u8*  mpk = (u8*)(qw + 3 * QSZ);
    u16* cx  = xqb;                 // alias: X-bf16 region is dead by then

    hipLaunchKernelGGL(cvt7m, dim3(2048), dim3(256), 0, stream,
                       Q, K, V, Wq, Wk, Wv, Wo, mask,
                       xqb, xkb, xvb, wqb, wkb, wvb, wob, mpk);
    hipLaunchKernelGGL(qkv_gemm2, dim3(NROW / 128, D_ / 128, 3), dim3(256), 0, stream,
                       xqb, xkb, xvb, wqb, wkb, wvb, qw, kw, vw);
    hipLaunchKernelGGL(attn_mfma11, dim3(S_ / 128, H_, B_), dim3(256), 0, stream,
                       qw, kw, vw, mpk, cx);
    hipLaunchKernelGGL(out_gemm2, dim3(NROW / 64, D_ / 64), dim3(256), 0, stream,
                       cx, wob, out);
}